// Round 10
// baseline (14313.107 us; speedup 1.0000x reference)
//
#include <hip/hip_runtime.h>

// ---------------------------------------------------------------------------
// TacotronMelDecoder on MI355X (gfx950) — precision-hardened persistent scan.
// R10: lean serial loop. zx[t] = x2_t @ Wx_top PRECOMPUTED (fp32) -> in-loop
// MFMA K drops 2048->1536 and the scattered x2p gather disappears; waves 0-1
// prefetch read-only data (mem PV slice, next zx) to keep phase C L2-warm;
// NO hist writes in the loop (k_hist reconstructs from rolling buffers);
// __expf gates. Sync = R8's RMW epoch barrier (3/step). Rolling write-once
// hroll/ucr/sr keep cached cross-block reads staleness-free without fences.
// ---------------------------------------------------------------------------

typedef unsigned short us16;
typedef unsigned int u32;
typedef unsigned long long u64;
typedef __attribute__((ext_vector_type(8))) short bf16x8;
typedef __attribute__((ext_vector_type(4))) float f32x4;

#define MFMA16 __builtin_amdgcn_mfma_f32_16x16x32_bf16
#define AGT __HIP_MEMORY_SCOPE_AGENT

__device__ __forceinline__ us16 f2bf(float f){
  u32 u = __builtin_bit_cast(u32, f);
  u += 0x7fffu + ((u >> 16) & 1u);
  return (us16)(u >> 16);
}
__device__ __forceinline__ float bf2f(us16 h){
  return __builtin_bit_cast(float, ((u32)h) << 16);
}
__device__ __forceinline__ float h2f(us16 u){
  _Float16 h = __builtin_bit_cast(_Float16, u); return (float)h;
}
__device__ __forceinline__ us16 f2h(float f){
  _Float16 h = (_Float16)f; return __builtin_bit_cast(us16, h);
}
__device__ __forceinline__ void split3(float v, us16& s0, us16& s1, us16& s2){
  s0 = f2bf(v); float r = v - bf2f(s0);
  s1 = f2bf(r); r -= bf2f(s1);
  s2 = f2bf(r);
}
__device__ __forceinline__ float tanh_fast(float x){
  float e = __expf(-2.f * fmaxf(x, -40.f));
  return (1.f - e) / (1.f + e);
}
__device__ __forceinline__ float sigf(float x){
  return 1.f / (1.f + __expf(-x));
}

__device__ __forceinline__ u32 aload32(const u32* p){
  return __hip_atomic_load(p, __ATOMIC_RELAXED, AGT);
}
__device__ __forceinline__ u64 aload64(const u64* p){
  return __hip_atomic_load(p, __ATOMIC_RELAXED, AGT);
}
__device__ __forceinline__ void astoref(float* p, float v){
  __hip_atomic_store(p, v, __ATOMIC_RELAXED, AGT);
}
__device__ __forceinline__ void aaddf(float* p, float v){
  __hip_atomic_fetch_add(p, v, __ATOMIC_RELAXED, AGT);
}
// MALL-direct 16B fp32 load (always fresh; tiny q reads)
__device__ __forceinline__ float4 aloadf4(const float* p){
  union { u64 u[2]; float4 f; } t;
  const u64* q = (const u64*)p;
  t.u[0] = aload64(q); t.u[1] = aload64(q + 1);
  return t.f;
}
// opacity: keep a loaded fragment in regs (non-rematerializable)
__device__ __forceinline__ bf16x8 pin_reg(bf16x8 v){
  f32x4 t = __builtin_bit_cast(f32x4, v);
  asm volatile("" : "+v"(t));
  return __builtin_bit_cast(bf16x8, t);
}
// 8 cached fp32 -> scaled triple-split bf16 fragments
__device__ __forceinline__ void f32_frag3(const float* p, float rs,
                                          bf16x8& f0, bf16x8& f1, bf16x8& f2){
  float4 t0 = *(const float4*)p;
  float4 t1 = *(const float4*)(p + 4);
  float tf[8] = {t0.x, t0.y, t0.z, t0.w, t1.x, t1.y, t1.z, t1.w};
#pragma unroll
  for (int i = 0; i < 8; ++i){
    float v = tf[i] * rs;
    us16 s0, s1, s2; split3(v, s0, s1, s2);
    f0[i] = (short)s0; f1[i] = (short)s1; f2[i] = (short)s2;
  }
}

// ---------------- workspace layout (bytes) ----------------
#define OFF_WTA    0ull            // 3 planes [4096][2048] bf16 (rows 512..2047 used; cols permuted u*4+gate)
#define OFF_WQT    50331648ull     // 3 planes [1024][1024] bf16 (Wq^T)
#define OFF_X2F    56623104ull     // [6400][512] f32 (prenet out)
#define OFF_KEYH   69730304ull     // [8192][1024] fp16 hi
#define OFF_KEYL   86507520ull     // [8192][1024] fp16 lo
#define OFF_X1     69730304ull     // alias over KEYH/KEYL (dead before keys written)
#define OFF_HIST   103284736ull    // [201][32][1536] bf16 (built post-loop by k_hist)
#define OFF_HROLL  123043840ull    // [201][32][1024] f32 h (rolling, write-once)
#define OFF_UCR    149389312ull    // [201][32][512] f32 raw ctx sums (rolling)
#define OFF_SR     162562048ull    // [201][32] f32 softmax sums (rolling; slot0=1)
#define OFF_QB     162587776ull    // [32][1024] f32 (non-rolling; MALL-direct reads)
#define OFF_CB     162718848ull    // [32][1024] f32 c state (block-private)
#define OFF_WAPN   162849920ull    // [1536][80] bf16 (Wa@Wp natural)
#define OFF_BPERM  163095680ull    // [4096] f32
#define OFF_BAR    163112064ull
#define OFF_ZX     163113088ull    // [200][32][4096] f32 precomputed x@WxTop (permuted cols)
#define TOTAL_WS   267970688ull

#define WTPL 8388608ull
#define WQPL 1048576ull

// ---------------- init (re-run every launch: replay-safe) ----------------
__global__ void k_zero_init(float* hroll0, float* ucr, float* sr, float* cbuf, u32* bar){
  u32 id = blockIdx.x * 256u + threadIdx.x;
  const u32 gs = 65536u;
  for (u32 i = id; i < 32768u;   i += gs) hroll0[i] = 0.f;
  for (u32 i = id; i < 3293184u; i += gs) ucr[i]  = 0.f;
  for (u32 i = id; i < 6432u;    i += gs) sr[i]   = (i < 32u) ? 1.f : 0.f;
  for (u32 i = id; i < 32768u;   i += gs) cbuf[i] = 0.f;
  for (u32 i = id; i < 256u;     i += gs) bar[i]  = 0u;
}

__global__ void k_bperm(const float* __restrict__ bl, float* __restrict__ bpm){
  int c = blockIdx.x * 256 + threadIdx.x;
  if (c < 4096) bpm[((c & 1023) << 2) | (c >> 10)] = bl[c];
}

// ---------------- transpose f32 -> 3 bf16 planes ----------------
__global__ void k_transp3(const float* __restrict__ src, us16* __restrict__ dst,
                          int srows, int scols, int ldd, long long pstride, int perm){
  __shared__ float tile[32][33];
  int bx = blockIdx.x * 32, by = blockIdx.y * 32;
  int tx = threadIdx.x & 31, ty = threadIdx.x >> 5;
#pragma unroll
  for (int i = 0; i < 4; ++i){
    int r = by + ty + i * 8, c = bx + tx;
    tile[ty + i * 8][tx] = (r < srows && c < scols) ? src[(size_t)r * scols + c] : 0.f;
  }
  __syncthreads();
#pragma unroll
  for (int i = 0; i < 4; ++i){
    int c = bx + ty + i * 8;
    int r = by + tx;
    if (c < scols && r < srows){
      int oc = perm ? (((c & 1023) << 2) | (c >> 10)) : c;
      float v = tile[tx][ty + i * 8];
      us16 s0, s1, s2; split3(v, s0, s1, s2);
      size_t base = (size_t)oc * ldd + r;
      dst[base] = s0; dst[(size_t)pstride + base] = s1; dst[2ull * pstride + base] = s2;
    }
  }
}

// ---------------- generic triple-split GEMM: C[M,N] = A[M,K] @ B[K,N] ----------------
// modes: 0 f32+bias+relu | 2 keys fp16 pair | 3 fold -> WTA planes (+Wh, perm)
//        4 bf16 plain | 5 mel f32 (+bias, row remap) | 6 f32 plain
//        7 zx f32 (row remap b*200+t -> t*32+b, col perm)
template<int NP, int AF, int BF>
__global__ void __launch_bounds__(256)
k_gemm3(const void* __restrict__ Ap, const void* __restrict__ Bp, void* __restrict__ outp,
        int M, int N, int K, int mode, const float* __restrict__ aux, int ldd){
  __shared__ us16 At[NP][128][72];
  __shared__ us16 Bt[NP][64][72];
  const int tid = threadIdx.x, wv = tid >> 6, lane = tid & 63;
  const int r0 = lane & 15, kg = lane >> 4;
  const int rb = blockIdx.x * 128, cb = blockIdx.y * 64;
  f32x4 acc[2][4];
#pragma unroll
  for (int a = 0; a < 2; ++a)
#pragma unroll
    for (int b = 0; b < 4; ++b) acc[a][b] = (f32x4){0.f, 0.f, 0.f, 0.f};

  const int nkt = (K + 63) >> 6;
  for (int kt = 0; kt < nkt; ++kt){
    const int kb = kt * 64;
    for (int e = tid; e < 8192; e += 256){
      int r = e >> 6, k = e & 63, ga = rb + r, gk = kb + k;
      bool ok = (ga < M) && (gk < K);
      if constexpr (AF){
        float v = ok ? ((const float*)Ap)[(size_t)ga * K + gk] : 0.f;
        us16 s0, s1, s2; split3(v, s0, s1, s2);
        At[0][r][k] = s0;
        if constexpr (NP == 3){ At[1][r][k] = s1; At[2][r][k] = s2; }
      } else {
        At[0][r][k] = ok ? ((const us16*)Ap)[(size_t)ga * K + gk] : (us16)0;
      }
    }
    for (int e = tid; e < 4096; e += 256){
      int kr = e >> 6, c = e & 63, gk = kb + kr, gc = cb + c;
      bool ok = (gk < K) && (gc < N);
      if constexpr (BF){
        float v = ok ? ((const float*)Bp)[(size_t)gk * N + gc] : 0.f;
        us16 s0, s1, s2; split3(v, s0, s1, s2);
        Bt[0][c][kr] = s0;
        if constexpr (NP == 3){ Bt[1][c][kr] = s1; Bt[2][c][kr] = s2; }
      } else {
        Bt[0][c][kr] = ok ? ((const us16*)Bp)[(size_t)gk * N + gc] : (us16)0;
      }
    }
    __syncthreads();
#pragma unroll
    for (int kk = 0; kk < 64; kk += 32){
      bf16x8 af[NP][2];
#pragma unroll
      for (int p = 0; p < NP; ++p){
        af[p][0] = *(const bf16x8*)&At[p][wv * 32 + r0][kk + kg * 8];
        af[p][1] = *(const bf16x8*)&At[p][wv * 32 + 16 + r0][kk + kg * 8];
      }
#pragma unroll
      for (int cf = 0; cf < 4; ++cf){
        bf16x8 bv[NP];
#pragma unroll
        for (int p = 0; p < NP; ++p) bv[p] = *(const bf16x8*)&Bt[p][cf * 16 + r0][kk + kg * 8];
#pragma unroll
        for (int rf = 0; rf < 2; ++rf){
          acc[rf][cf] = MFMA16(af[0][rf], bv[0], acc[rf][cf], 0, 0, 0);
          if constexpr (NP == 3){
            acc[rf][cf] = MFMA16(af[0][rf], bv[1], acc[rf][cf], 0, 0, 0);
            acc[rf][cf] = MFMA16(af[1][rf], bv[0], acc[rf][cf], 0, 0, 0);
            acc[rf][cf] = MFMA16(af[0][rf], bv[2], acc[rf][cf], 0, 0, 0);
            acc[rf][cf] = MFMA16(af[1][rf], bv[1], acc[rf][cf], 0, 0, 0);
            acc[rf][cf] = MFMA16(af[2][rf], bv[0], acc[rf][cf], 0, 0, 0);
          }
        }
      }
    }
    __syncthreads();
  }
  us16* o16 = (us16*)outp; float* of = (float*)outp;
#pragma unroll
  for (int rf = 0; rf < 2; ++rf)
#pragma unroll
    for (int cf = 0; cf < 4; ++cf)
#pragma unroll
      for (int i = 0; i < 4; ++i){
        int r = rb + wv * 32 + rf * 16 + kg * 4 + i;
        int c = cb + cf * 16 + r0;
        if (r >= M || c >= N) continue;
        float v = acc[rf][cf][i];
        if (mode == 0){
          of[(size_t)r * ldd + c] = fmaxf(v + aux[c], 0.f);
        } else if (mode == 2){
          us16 hh = f2h(v); float rem = v - h2f(hh); us16 hl = f2h(rem);
          size_t b2 = (size_t)r * 1024 + c;
          o16[b2] = hh; o16[WTPL + b2] = hl;
        } else if (mode == 3){
          float w = v + (r < 1024 ? aux[(size_t)r * 4096 + c] : 0.f);
          int pc = (c & 1023) * 4 + (c >> 10);
          us16 s0, s1, s2; split3(w, s0, s1, s2);
          size_t b2 = (size_t)pc * 2048 + 512 + r;
          o16[b2] = s0; o16[WTPL + b2] = s1; o16[2 * WTPL + b2] = s2;
        } else if (mode == 4){
          o16[(size_t)r * ldd + c] = f2bf(v);
        } else if (mode == 5){
          of[((size_t)(r & 31) * 200 + (r >> 5)) * 80 + c] = v + aux[c];
        } else if (mode == 7){
          int pc = (c & 1023) * 4 + (c >> 10);
          of[((size_t)(r % 200) * 32 + (r / 200)) * 4096 + pc] = v;
        } else {
          of[(size_t)r * ldd + c] = v;
        }
      }
}

// ---------------- global barrier (monotonic epoch, 8 groups of 32) ----------------
__device__ __forceinline__ void gbar(u32* bar, u32 ep, int tid, int blk){
  __syncthreads();
  if (tid == 0){
    asm volatile("s_waitcnt vmcnt(0)" ::: "memory");
    u32 g = (u32)(blk >> 5);
    u32 old = __hip_atomic_fetch_add(&bar[g * 32], 1u, __ATOMIC_RELAXED, AGT);
    if (old == 32u * ep - 1u){
      u32 r = __hip_atomic_fetch_add(&bar[248], 1u, __ATOMIC_RELAXED, AGT);
      if (r == 8u * ep - 1u)
        __hip_atomic_store(&bar[252], ep, __ATOMIC_RELAXED, AGT);
    }
    while (aload32(&bar[252]) < ep) __builtin_amdgcn_s_sleep(1);
    __builtin_amdgcn_sched_barrier(0);
  }
  __syncthreads();
}

// ---------------- persistent scan kernel ----------------
struct CoopA {
  const us16 *wta, *wqt, *kh, *kl;
  const float *mem, *vatt, *bperm, *zx;
  float *hroll, *ucr, *sr, *qb, *cbuf;
  u32 *bar;
};

__global__ void __launch_bounds__(512, 1) k_coop(CoopA a){
  __shared__ us16 khi[32][1024];
  __shared__ us16 klo[32][1024];
  __shared__ float zp[8][512];
  __shared__ float esc[32];
  __shared__ float rs_lds[32];

  // one-time invalidate: kill stale lines from a previous graph replay
  __builtin_amdgcn_fence(__ATOMIC_ACQUIRE, "agent");

  const int tid = threadIdx.x, blk = blockIdx.x;
  const int wv = tid >> 6, lane = tid & 63;
  const int r0 = lane & 15, kg = lane >> 4;
  const int cb_b = blk >> 3, cb_s0 = (blk & 7) * 32;   // phase-C identity
  const int colbase = blk * 16;
  const int u0 = lane * 16;

  // WTA slice (h|ctx rows only, K=1536) pinned in regs (72 VGPR-equiv)
  bf16x8 wr[8][3];
  if (wv >= 2){
#pragma unroll
    for (int ks = 0; ks < 8; ++ks){
      const size_t wb = (size_t)(colbase + r0) * 2048 + 512 +
                        (size_t)(wv - 2) * 256 + ks * 32 + kg * 8;
#pragma unroll
      for (int p = 0; p < 3; ++p)
        wr[ks][p] = pin_reg(*(const bf16x8*)&a.wta[(size_t)p * WTPL + wb]);
    }
  }

  // keys slice resident in LDS for all 200 steps
  {
    const size_t kbase = ((size_t)(cb_b * 256 + cb_s0)) * 1024;
    for (int i = tid; i < 4096; i += 512){
      int r = i >> 7, c8 = (i & 127) * 8;
      *(bf16x8*)&khi[r][c8] = *(const bf16x8*)&a.kh[kbase + (size_t)r * 1024 + c8];
      *(bf16x8*)&klo[r][c8] = *(const bf16x8*)&a.kl[kbase + (size_t)r * 1024 + c8];
    }
  }
  __syncthreads();

  u32 ep = 0;
  for (int t = 0; t < 200; ++t){
    // ===== phase A: z = zx[t] + [h|ctx] @ WTA (regs); gates =====
    {
      if (tid < 32) rs_lds[tid] = 1.f / a.sr[(size_t)t * 32 + tid];
      __syncthreads();
      if (wv < 2){
        // prefetch read-only data for later phases (L2 warm): mem PV slice + next zx lines
        const float* mslice = a.mem + ((size_t)(cb_b * 256 + cb_s0)) * 512;
        float s = mslice[tid * 128] + mslice[tid * 128 + 32] +
                  mslice[tid * 128 + 64] + mslice[tid * 128 + 96];
        if (t < 199)
          s += a.zx[((size_t)(t + 1) * 32 + (tid & 31)) * 4096 + colbase];
        asm volatile("" :: "v"(s));
      } else {
        f32x4 acc0 = (f32x4){0.f,0.f,0.f,0.f}, acc1 = acc0;
#pragma unroll
        for (int ks = 0; ks < 8; ++ks){
          const int kl2 = (wv - 2) * 256 + ks * 32 + kg * 8;   // 0..1535
          bf16x8 w0 = wr[ks][0], w1 = wr[ks][1], w2 = wr[ks][2];
          bf16x8 a00, a01, a02, a10, a11, a12;
          if (wv < 6){
            const float* hp0 = a.hroll + (size_t)t * 32768 + (size_t)r0 * 1024 + kl2;
            f32_frag3(hp0,         1.f, a00, a01, a02);
            f32_frag3(hp0 + 16384, 1.f, a10, a11, a12);
          } else {
            const int ek = kl2 - 1024;
            const float* up = a.ucr + (size_t)t * 16384 + (size_t)r0 * 512 + ek;
            f32_frag3(up,        rs_lds[r0],      a00, a01, a02);
            f32_frag3(up + 8192, rs_lds[r0 + 16], a10, a11, a12);
          }
          acc0 = MFMA16(a00, w0, acc0, 0,0,0); acc0 = MFMA16(a00, w1, acc0, 0,0,0);
          acc0 = MFMA16(a01, w0, acc0, 0,0,0); acc0 = MFMA16(a00, w2, acc0, 0,0,0);
          acc0 = MFMA16(a01, w1, acc0, 0,0,0); acc0 = MFMA16(a02, w0, acc0, 0,0,0);
          acc1 = MFMA16(a10, w0, acc1, 0,0,0); acc1 = MFMA16(a10, w1, acc1, 0,0,0);
          acc1 = MFMA16(a11, w0, acc1, 0,0,0); acc1 = MFMA16(a10, w2, acc1, 0,0,0);
          acc1 = MFMA16(a11, w1, acc1, 0,0,0); acc1 = MFMA16(a12, w0, acc1, 0,0,0);
        }
#pragma unroll
        for (int i = 0; i < 4; ++i){
          zp[wv][(kg * 4 + i) * 16 + r0]      = acc0[i];
          zp[wv][(16 + kg * 4 + i) * 16 + r0] = acc1[i];
        }
      }
      __syncthreads();
      float z = 0.f;
#pragma unroll
      for (int w = 2; w < 8; ++w) z += zp[w][tid];
      z += a.zx[((size_t)t * 32 + (tid >> 4)) * 4096 + colbase + (tid & 15)];
      z += a.bperm[colbase + (tid & 15)];
      __syncthreads();
      zp[0][tid] = z;
      __syncthreads();
      if (tid < 128){
        int b = tid >> 2, ul = tid & 3, u = blk * 4 + ul;
        float zi = zp[0][b * 16 + ul * 4 + 0];
        float zf = zp[0][b * 16 + ul * 4 + 1];
        float zg = zp[0][b * 16 + ul * 4 + 2];
        float zo = zp[0][b * 16 + ul * 4 + 3];
        float co = a.cbuf[b * 1024 + u];
        float cn = sigf(zf) * co + sigf(zi) * tanh_fast(zg);
        float hn = sigf(zo) * tanh_fast(cn);
        a.cbuf[b * 1024 + u] = cn;                       // block-private
        astoref(&a.hroll[(size_t)(t + 1) * 32768 + b * 1024 + u], hn);
      }
    }
    gbar(a.bar, ++ep, tid, blk);

    // ===== phase B: q = h_new @ Wq (blocks 0..63; WQT cached) =====
    if (blk < 64){
      f32x4 acc0 = (f32x4){0.f,0.f,0.f,0.f}, acc1 = acc0;
#pragma unroll
      for (int ks = 0; ks < 4; ++ks){
        const int kf = wv * 128 + ks * 32 + kg * 8;
        const size_t wb = (size_t)(colbase + r0) * 1024 + kf;
        bf16x8 w0 = *(const bf16x8*)&a.wqt[wb];
        bf16x8 w1 = *(const bf16x8*)&a.wqt[WQPL + wb];
        bf16x8 w2 = *(const bf16x8*)&a.wqt[2 * WQPL + wb];
        bf16x8 a00, a01, a02, a10, a11, a12;
        const float* hp0 = a.hroll + (size_t)(t + 1) * 32768 + (size_t)r0 * 1024 + kf;
        f32_frag3(hp0,         1.f, a00, a01, a02);
        f32_frag3(hp0 + 16384, 1.f, a10, a11, a12);
        acc0 = MFMA16(a00, w0, acc0, 0,0,0); acc0 = MFMA16(a00, w1, acc0, 0,0,0);
        acc0 = MFMA16(a01, w0, acc0, 0,0,0); acc0 = MFMA16(a00, w2, acc0, 0,0,0);
        acc0 = MFMA16(a01, w1, acc0, 0,0,0); acc0 = MFMA16(a02, w0, acc0, 0,0,0);
        acc1 = MFMA16(a10, w0, acc1, 0,0,0); acc1 = MFMA16(a10, w1, acc1, 0,0,0);
        acc1 = MFMA16(a11, w0, acc1, 0,0,0); acc1 = MFMA16(a10, w2, acc1, 0,0,0);
        acc1 = MFMA16(a11, w1, acc1, 0,0,0); acc1 = MFMA16(a12, w0, acc1, 0,0,0);
      }
#pragma unroll
      for (int i = 0; i < 4; ++i){
        zp[wv][(kg * 4 + i) * 16 + r0]      = acc0[i];
        zp[wv][(16 + kg * 4 + i) * 16 + r0] = acc1[i];
      }
      __syncthreads();
      float q = 0.f;
#pragma unroll
      for (int w = 0; w < 8; ++w) q += zp[w][tid];
      astoref(&a.qb[(size_t)(tid >> 4) * 1024 + colbase + (tid & 15)], q);
    }
    gbar(a.bar, ++ep, tid, blk);

    // ===== phase C: score + exp + atomic ctx/sums (block = (b, s-slice32)) =====
    {
      float qv[16], vv[16];
      {
        const float* qp = a.qb + (size_t)cb_b * 1024 + u0;
        float4 q0 = aloadf4(qp), q1 = aloadf4(qp + 4);
        float4 q2 = aloadf4(qp + 8), q3 = aloadf4(qp + 12);
        qv[0]=q0.x; qv[1]=q0.y; qv[2]=q0.z; qv[3]=q0.w;
        qv[4]=q1.x; qv[5]=q1.y; qv[6]=q1.z; qv[7]=q1.w;
        qv[8]=q2.x; qv[9]=q2.y; qv[10]=q2.z; qv[11]=q2.w;
        qv[12]=q3.x; qv[13]=q3.y; qv[14]=q3.z; qv[15]=q3.w;
        float4 v0 = *(const float4*)(a.vatt + u0);
        float4 v1 = *(const float4*)(a.vatt + u0 + 4);
        float4 v2 = *(const float4*)(a.vatt + u0 + 8);
        float4 v3 = *(const float4*)(a.vatt + u0 + 12);
        vv[0]=v0.x; vv[1]=v0.y; vv[2]=v0.z; vv[3]=v0.w;
        vv[4]=v1.x; vv[5]=v1.y; vv[6]=v1.z; vv[7]=v1.w;
        vv[8]=v2.x; vv[9]=v2.y; vv[10]=v2.z; vv[11]=v2.w;
        vv[12]=v3.x; vv[13]=v3.y; vv[14]=v3.z; vv[15]=v3.w;
      }
#pragma unroll
      for (int m = 0; m < 4; ++m){
        const int sl = wv * 4 + m;
        bf16x8 h0 = *(const bf16x8*)&khi[sl][u0];
        bf16x8 h1 = *(const bf16x8*)&khi[sl][u0 + 8];
        bf16x8 l0 = *(const bf16x8*)&klo[sl][u0];
        bf16x8 l1 = *(const bf16x8*)&klo[sl][u0 + 8];
        float part = 0.f;
#pragma unroll
        for (int j = 0; j < 8; ++j){
          float kva = h2f((us16)h0[j]) + h2f((us16)l0[j]);
          part += vv[j] * tanh_fast(kva + qv[j]);
          float kvb = h2f((us16)h1[j]) + h2f((us16)l1[j]);
          part += vv[8 + j] * tanh_fast(kvb + qv[8 + j]);
        }
#pragma unroll
        for (int off = 32; off; off >>= 1) part += __shfl_xor(part, off);
        if (lane == 0) esc[sl] = __expf(part);   // max-free softmax (|score| small)
      }
      __syncthreads();
      if (tid == 0){
        float bs = 0.f;
#pragma unroll
        for (int i = 0; i < 32; ++i) bs += esc[i];
        aaddf(&a.sr[(size_t)(t + 1) * 32 + cb_b], bs);
      }
      {
        float ac0 = 0.f, ac1 = 0.f, ac2 = 0.f, ac3 = 0.f;
        const float* mrow = a.mem + ((size_t)(cb_b * 256 + cb_s0)) * 512 + tid;
#pragma unroll
        for (int j = 0; j < 32; j += 4){
          ac0 += esc[j]     * mrow[(size_t)j * 512];
          ac1 += esc[j + 1] * mrow[(size_t)(j + 1) * 512];
          ac2 += esc[j + 2] * mrow[(size_t)(j + 2) * 512];
          ac3 += esc[j + 3] * mrow[(size_t)(j + 3) * 512];
        }
        aaddf(&a.ucr[(size_t)(t + 1) * 16384 + cb_b * 512 + tid], (ac0 + ac1) + (ac2 + ac3));
      }
    }
    gbar(a.bar, ++ep, tid, blk);
  }
}

// ---------------- hist reconstruction (post-loop, pure function of rolls) ----
__global__ void k_hist(const float* __restrict__ hroll, const float* __restrict__ ucr,
                       const float* __restrict__ sr, us16* __restrict__ hist){
  int row = blockIdx.x;                 // 0..6431 = t*32 + b
  int t = row >> 5, b = row & 31;
  float rs = 1.f / sr[(size_t)t * 32 + b];
  for (int c = threadIdx.x; c < 1536; c += 256){
    us16 v;
    if (c < 1024) v = f2bf(hroll[(size_t)t * 32768 + b * 1024 + c]);
    else          v = f2bf(ucr[(size_t)t * 16384 + b * 512 + (c - 1024)] * rs);
    hist[(size_t)row * 1536 + c] = v;
  }
}

__global__ void k_copy_hc(const float* __restrict__ h, const float* __restrict__ c,
                          float* __restrict__ out){
  int i = blockIdx.x * 256 + threadIdx.x;
  if (i < 32768){
    out[512000 + i] = h[i];
    out[544768 + i] = c[i];
  }
}

// ---------------------------------------------------------------------------
extern "C" void kernel_launch(void* const* d_in, const int* in_sizes, int n_in,
                              void* d_out, int out_size, void* d_ws, size_t ws_size,
                              hipStream_t stream){
  const float* inputs = (const float*)d_in[0];
  const float* memory = (const float*)d_in[1];
  const float* W1     = (const float*)d_in[2];
  const float* b1     = (const float*)d_in[3];
  const float* W2     = (const float*)d_in[4];
  const float* b2     = (const float*)d_in[5];
  const float* Wx     = (const float*)d_in[6];
  const float* Wh     = (const float*)d_in[7];
  const float* b_lstm = (const float*)d_in[8];
  const float* Wm     = (const float*)d_in[9];
  const float* Wq     = (const float*)d_in[10];
  const float* v_att  = (const float*)d_in[11];
  const float* Wa     = (const float*)d_in[12];
  const float* Wp     = (const float*)d_in[13];
  const float* bp     = (const float*)d_in[14];
  float* out = (float*)d_out;
  char* ws = (char*)d_ws;
  if (ws_size < TOTAL_WS) return;

  us16* WTA    = (us16*)(ws + OFF_WTA);
  us16* WQT    = (us16*)(ws + OFF_WQT);
  float* X2F   = (float*)(ws + OFF_X2F);
  us16* KEYH   = (us16*)(ws + OFF_KEYH);
  float* X1    = (float*)(ws + OFF_X1);
  us16* HIST   = (us16*)(ws + OFF_HIST);
  float* HROLL = (float*)(ws + OFF_HROLL);
  float* UCR   = (float*)(ws + OFF_UCR);
  float* SR    = (float*)(ws + OFF_SR);
  float* QB    = (float*)(ws + OFF_QB);
  float* CB    = (float*)(ws + OFF_CB);
  us16* WAPN   = (us16*)(ws + OFF_WAPN);
  float* BPM   = (float*)(ws + OFF_BPERM);
  u32*  BAR    = (u32*)(ws + OFF_BAR);
  float* ZX    = (float*)(ws + OFF_ZX);

  k_zero_init<<<256, 256, 0, stream>>>(HROLL, UCR, SR, CB, BAR);
  k_bperm<<<16, 256, 0, stream>>>(b_lstm, BPM);
  k_transp3<<<dim3(32, 32), 256, 0, stream>>>(Wq, WQT, 1024, 1024, 1024, (long long)WQPL, 0);

  // fold: WTA rows 512..2047 = [Wh + WaTop@Wxb ; WaBot@Wxb], gate-permuted, triple-split
  k_gemm3<3,1,1><<<dim3(12, 64), 256, 0, stream>>>(Wa, Wx + (size_t)512 * 4096, WTA,
                                                   1536, 4096, 1024, 3, Wh, 0);
  // WapN = Wa @ Wp  [1536][80] bf16
  k_gemm3<3,1,1><<<dim3(12, 2), 256, 0, stream>>>(Wa, Wp, WAPN, 1536, 80, 1024, 4, nullptr, 80);
  // prenet 1: x1 = relu(inputs @ W1 + b1)  f32
  k_gemm3<3,1,1><<<dim3(50, 16), 256, 0, stream>>>(inputs, W1, X1, 6400, 1024, 80, 0, b1, 1024);
  // prenet 2: x2 = relu(x1 @ W2 + b2)  f32
  k_gemm3<3,1,1><<<dim3(50, 8), 256, 0, stream>>>(X1, W2, X2F, 6400, 512, 1024, 0, b2, 512);
  // zx = x2 @ Wx_top  f32, row remap (b*200+t -> t*32+b), col perm
  k_gemm3<3,1,1><<<dim3(50, 64), 256, 0, stream>>>(X2F, Wx, ZX, 6400, 4096, 512, 7, nullptr, 0);
  // keys = memory @ Wm -> fp16 pair (overwrites X1 alias region; X1 dead now)
  k_gemm3<3,1,1><<<dim3(64, 16), 256, 0, stream>>>(memory, Wm, KEYH, 8192, 1024, 512, 2, nullptr, 1024);

  CoopA ca;
  ca.wta = WTA; ca.wqt = WQT; ca.kh = KEYH; ca.kl = KEYH + WTPL;
  ca.mem = memory; ca.vatt = v_att; ca.bperm = BPM; ca.zx = ZX;
  ca.hroll = HROLL; ca.ucr = UCR; ca.sr = SR; ca.qb = QB; ca.cbuf = CB; ca.bar = BAR;
  void* args[] = {(void*)&ca};
  hipLaunchCooperativeKernel((const void*)k_coop, dim3(256), dim3(512), args, 0, stream);

  // rebuild hist from rolling buffers
  k_hist<<<6432, 256, 0, stream>>>(HROLL, UCR, SR, HIST);
  // mel = hist[1..200] @ WapN + bp
  k_gemm3<1,0,0><<<dim3(50, 2), 256, 0, stream>>>(HIST + (size_t)32 * 1536, WAPN, out,
                                                  6400, 80, 1536, 5, bp, 0);
  // attn = hist[200] @ Wa
  k_gemm3<1,0,1><<<dim3(1, 16), 256, 0, stream>>>(HIST + (size_t)200 * 32 * 1536, Wa,
                                                  out + 577536, 32, 1024, 1536, 6, nullptr, 1024);
  k_copy_hc<<<128, 256, 0, stream>>>(HROLL + (size_t)200 * 32768, CB, out);
}

// Round 11
// 12641.306 us; speedup vs baseline: 1.1322x; 1.1322x over previous
//
#include <hip/hip_runtime.h>

// ---------------------------------------------------------------------------
// TacotronMelDecoder on MI355X (gfx950) — precision-hardened persistent scan.
// R11: dedicated-checker barrier (arrival STORES + block0 polls all + single
// release word) replacing the RMW-chain barrier (~5us -> ~1.5us/rendezvous);
// h published pre-split as 3 rolling bf16 planes (consumer split3 removed
// from phases A/B); ZX reverted (R10: +1.7ms prologue, zero loop gain);
// hist rebuilt post-loop (k_hist). Rolling write-once buffers keep cached
// cross-block reads staleness-free with no fences. 3 rendezvous/step.
// ---------------------------------------------------------------------------

typedef unsigned short us16;
typedef unsigned int u32;
typedef unsigned long long u64;
typedef __attribute__((ext_vector_type(8))) short bf16x8;
typedef __attribute__((ext_vector_type(4))) float f32x4;

#define MFMA16 __builtin_amdgcn_mfma_f32_16x16x32_bf16
#define AGT __HIP_MEMORY_SCOPE_AGENT

__device__ __forceinline__ us16 f2bf(float f){
  u32 u = __builtin_bit_cast(u32, f);
  u += 0x7fffu + ((u >> 16) & 1u);
  return (us16)(u >> 16);
}
__device__ __forceinline__ float bf2f(us16 h){
  return __builtin_bit_cast(float, ((u32)h) << 16);
}
__device__ __forceinline__ float h2f(us16 u){
  _Float16 h = __builtin_bit_cast(_Float16, u); return (float)h;
}
__device__ __forceinline__ us16 f2h(float f){
  _Float16 h = (_Float16)f; return __builtin_bit_cast(us16, h);
}
__device__ __forceinline__ void split3(float v, us16& s0, us16& s1, us16& s2){
  s0 = f2bf(v); float r = v - bf2f(s0);
  s1 = f2bf(r); r -= bf2f(s1);
  s2 = f2bf(r);
}
__device__ __forceinline__ float tanh_fast(float x){
  float e = __expf(-2.f * fmaxf(x, -40.f));
  return (1.f - e) / (1.f + e);
}
__device__ __forceinline__ float sigf(float x){
  return 1.f / (1.f + __expf(-x));
}

__device__ __forceinline__ u32 aload32(const u32* p){
  return __hip_atomic_load(p, __ATOMIC_RELAXED, AGT);
}
__device__ __forceinline__ u64 aload64(const u64* p){
  return __hip_atomic_load(p, __ATOMIC_RELAXED, AGT);
}
__device__ __forceinline__ void astore16(us16* p, us16 v){
  __hip_atomic_store(p, v, __ATOMIC_RELAXED, AGT);
}
__device__ __forceinline__ void astoref(float* p, float v){
  __hip_atomic_store(p, v, __ATOMIC_RELAXED, AGT);
}
__device__ __forceinline__ void sigflag(u32* p, u32 v){
  __hip_atomic_store(p, v, __ATOMIC_RELAXED, AGT);
}
__device__ __forceinline__ void aaddf(float* p, float v){
  __hip_atomic_fetch_add(p, v, __ATOMIC_RELAXED, AGT);
}
// plain cached 16B load (rolling addresses -> no staleness)
__device__ __forceinline__ bf16x8 ld16(const us16* p){
  return *(const bf16x8*)p;
}
// MALL-direct 16B fp32 load (always fresh; tiny q reads)
__device__ __forceinline__ float4 aloadf4(const float* p){
  union { u64 u[2]; float4 f; } t;
  const u64* q = (const u64*)p;
  t.u[0] = aload64(q); t.u[1] = aload64(q + 1);
  return t.f;
}
// opacity: keep a loaded fragment in regs (non-rematerializable)
__device__ __forceinline__ bf16x8 pin_reg(bf16x8 v){
  f32x4 t = __builtin_bit_cast(f32x4, v);
  asm volatile("" : "+v"(t));
  return __builtin_bit_cast(bf16x8, t);
}
// 8 cached fp32 -> scaled triple-split bf16 fragments (ctx path)
__device__ __forceinline__ void f32_frag3(const float* p, float rs,
                                          bf16x8& f0, bf16x8& f1, bf16x8& f2){
  float4 t0 = *(const float4*)p;
  float4 t1 = *(const float4*)(p + 4);
  float tf[8] = {t0.x, t0.y, t0.z, t0.w, t1.x, t1.y, t1.z, t1.w};
#pragma unroll
  for (int i = 0; i < 8; ++i){
    float v = tf[i] * rs;
    us16 s0, s1, s2; split3(v, s0, s1, s2);
    f0[i] = (short)s0; f1[i] = (short)s1; f2[i] = (short)s2;
  }
}

// ---------------- workspace layout (bytes) ----------------
#define OFF_WTA    0ull            // 3 planes [4096][2048] bf16 (cols permuted u*4+gate)
#define OFF_WQT    50331648ull     // 3 planes [1024][1024] bf16 (Wq^T)
#define OFF_X2P    56623104ull     // 3 planes [32*200][512] bf16 (prenet out)
#define OFF_KEYH   76283904ull     // [8192][1024] fp16 hi
#define OFF_KEYL   93061120ull     // [8192][1024] fp16 lo
#define OFF_X1     76283904ull     // alias over KEYH/KEYL (dead before keys written)
#define OFF_HIST   109838336ull    // [201][32][1536] bf16 (built post-loop by k_hist)
#define OFF_HPR    129597440ull    // [201][3][32][1024] bf16 h planes (rolling)
#define OFF_UCR    169115648ull    // [201][32][512] f32 raw ctx sums (rolling)
#define OFF_SR     182288384ull    // [201][32] f32 softmax sums (rolling; slot0=1)
#define OFF_QB     182314112ull    // [32][1024] f32 (non-rolling; MALL-direct reads)
#define OFF_CB     182445184ull    // [32][1024] f32 c state (block-private)
#define OFF_HF     182576256ull    // [32][1024] f32 final h (plain)
#define OFF_WAPN   182707328ull    // [1536][80] bf16 (Wa@Wp natural)
#define OFF_BPERM  182953088ull    // [4096] f32
#define OFF_ARR    182969472ull    // 256 x 16 u32 arrival epochs + release word
#define TOTAL_WS   182987776ull

#define WTPL 8388608ull
#define WQPL 1048576ull
#define X2PL 3276800ull

// ---------------- init (re-run every launch: replay-safe) ----------------
__global__ void k_zero_init(u32* hpr0, float* ucr, float* sr, float* cbuf, u32* arr){
  u32 id = blockIdx.x * 256u + threadIdx.x;
  const u32 gs = 65536u;
  for (u32 i = id; i < 49152u;   i += gs) hpr0[i] = 0u;     // hp slot 0 (3 planes)
  for (u32 i = id; i < 3293184u; i += gs) ucr[i]  = 0.f;
  for (u32 i = id; i < 6432u;    i += gs) sr[i]   = (i < 32u) ? 1.f : 0.f;
  for (u32 i = id; i < 32768u;   i += gs) cbuf[i] = 0.f;
  for (u32 i = id; i < 4352u;    i += gs) arr[i]  = 0u;
}

__global__ void k_bperm(const float* __restrict__ bl, float* __restrict__ bpm){
  int c = blockIdx.x * 256 + threadIdx.x;
  if (c < 4096) bpm[((c & 1023) << 2) | (c >> 10)] = bl[c];
}

// ---------------- transpose f32 -> 3 bf16 planes (+optional gate perm) ----------------
__global__ void k_transp3(const float* __restrict__ src, us16* __restrict__ dst,
                          int srows, int scols, int ldd, long long pstride, int perm){
  __shared__ float tile[32][33];
  int bx = blockIdx.x * 32, by = blockIdx.y * 32;
  int tx = threadIdx.x & 31, ty = threadIdx.x >> 5;
#pragma unroll
  for (int i = 0; i < 4; ++i){
    int r = by + ty + i * 8, c = bx + tx;
    tile[ty + i * 8][tx] = (r < srows && c < scols) ? src[(size_t)r * scols + c] : 0.f;
  }
  __syncthreads();
#pragma unroll
  for (int i = 0; i < 4; ++i){
    int c = bx + ty + i * 8;
    int r = by + tx;
    if (c < scols && r < srows){
      int oc = perm ? (((c & 1023) << 2) | (c >> 10)) : c;
      float v = tile[tx][ty + i * 8];
      us16 s0, s1, s2; split3(v, s0, s1, s2);
      size_t base = (size_t)oc * ldd + r;
      dst[base] = s0; dst[(size_t)pstride + base] = s1; dst[2ull * pstride + base] = s2;
    }
  }
}

// ---------------- generic triple-split GEMM: C[M,N] = A[M,K] @ B[K,N] ----------------
// modes: 0 f32+bias+relu | 1 relu -> x2 triple planes | 2 keys fp16 pair
//        3 fold -> WTA planes (+Wh, perm) | 4 bf16 plain | 5 mel f32 | 6 f32 plain
template<int NP, int AF, int BF>
__global__ void __launch_bounds__(256)
k_gemm3(const void* __restrict__ Ap, const void* __restrict__ Bp, void* __restrict__ outp,
        int M, int N, int K, int mode, const float* __restrict__ aux, int ldd){
  __shared__ us16 At[NP][128][72];
  __shared__ us16 Bt[NP][64][72];
  const int tid = threadIdx.x, wv = tid >> 6, lane = tid & 63;
  const int r0 = lane & 15, kg = lane >> 4;
  const int rb = blockIdx.x * 128, cb = blockIdx.y * 64;
  f32x4 acc[2][4];
#pragma unroll
  for (int a = 0; a < 2; ++a)
#pragma unroll
    for (int b = 0; b < 4; ++b) acc[a][b] = (f32x4){0.f, 0.f, 0.f, 0.f};

  const int nkt = (K + 63) >> 6;
  for (int kt = 0; kt < nkt; ++kt){
    const int kb = kt * 64;
    for (int e = tid; e < 8192; e += 256){
      int r = e >> 6, k = e & 63, ga = rb + r, gk = kb + k;
      bool ok = (ga < M) && (gk < K);
      if constexpr (AF){
        float v = ok ? ((const float*)Ap)[(size_t)ga * K + gk] : 0.f;
        us16 s0, s1, s2; split3(v, s0, s1, s2);
        At[0][r][k] = s0;
        if constexpr (NP == 3){ At[1][r][k] = s1; At[2][r][k] = s2; }
      } else {
        At[0][r][k] = ok ? ((const us16*)Ap)[(size_t)ga * K + gk] : (us16)0;
      }
    }
    for (int e = tid; e < 4096; e += 256){
      int kr = e >> 6, c = e & 63, gk = kb + kr, gc = cb + c;
      bool ok = (gk < K) && (gc < N);
      if constexpr (BF){
        float v = ok ? ((const float*)Bp)[(size_t)gk * N + gc] : 0.f;
        us16 s0, s1, s2; split3(v, s0, s1, s2);
        Bt[0][c][kr] = s0;
        if constexpr (NP == 3){ Bt[1][c][kr] = s1; Bt[2][c][kr] = s2; }
      } else {
        Bt[0][c][kr] = ok ? ((const us16*)Bp)[(size_t)gk * N + gc] : (us16)0;
      }
    }
    __syncthreads();
#pragma unroll
    for (int kk = 0; kk < 64; kk += 32){
      bf16x8 af[NP][2];
#pragma unroll
      for (int p = 0; p < NP; ++p){
        af[p][0] = *(const bf16x8*)&At[p][wv * 32 + r0][kk + kg * 8];
        af[p][1] = *(const bf16x8*)&At[p][wv * 32 + 16 + r0][kk + kg * 8];
      }
#pragma unroll
      for (int cf = 0; cf < 4; ++cf){
        bf16x8 bv[NP];
#pragma unroll
        for (int p = 0; p < NP; ++p) bv[p] = *(const bf16x8*)&Bt[p][cf * 16 + r0][kk + kg * 8];
#pragma unroll
        for (int rf = 0; rf < 2; ++rf){
          acc[rf][cf] = MFMA16(af[0][rf], bv[0], acc[rf][cf], 0, 0, 0);
          if constexpr (NP == 3){
            acc[rf][cf] = MFMA16(af[0][rf], bv[1], acc[rf][cf], 0, 0, 0);
            acc[rf][cf] = MFMA16(af[1][rf], bv[0], acc[rf][cf], 0, 0, 0);
            acc[rf][cf] = MFMA16(af[0][rf], bv[2], acc[rf][cf], 0, 0, 0);
            acc[rf][cf] = MFMA16(af[1][rf], bv[1], acc[rf][cf], 0, 0, 0);
            acc[rf][cf] = MFMA16(af[2][rf], bv[0], acc[rf][cf], 0, 0, 0);
          }
        }
      }
    }
    __syncthreads();
  }
  us16* o16 = (us16*)outp; float* of = (float*)outp;
#pragma unroll
  for (int rf = 0; rf < 2; ++rf)
#pragma unroll
    for (int cf = 0; cf < 4; ++cf)
#pragma unroll
      for (int i = 0; i < 4; ++i){
        int r = rb + wv * 32 + rf * 16 + kg * 4 + i;
        int c = cb + cf * 16 + r0;
        if (r >= M || c >= N) continue;
        float v = acc[rf][cf][i];
        if (mode == 0){
          of[(size_t)r * ldd + c] = fmaxf(v + aux[c], 0.f);
        } else if (mode == 1){
          v = fmaxf(v + aux[c], 0.f);
          us16 s0, s1, s2; split3(v, s0, s1, s2);
          size_t b2 = (size_t)r * ldd + c;
          o16[b2] = s0; o16[X2PL + b2] = s1; o16[2 * X2PL + b2] = s2;
        } else if (mode == 2){
          us16 hh = f2h(v); float rem = v - h2f(hh); us16 hl = f2h(rem);
          size_t b2 = (size_t)r * 1024 + c;
          o16[b2] = hh; o16[WTPL + b2] = hl;
        } else if (mode == 3){
          float w = v + (r < 1024 ? aux[(size_t)r * 4096 + c] : 0.f);
          int pc = (c & 1023) * 4 + (c >> 10);
          us16 s0, s1, s2; split3(w, s0, s1, s2);
          size_t b2 = (size_t)pc * 2048 + 512 + r;
          o16[b2] = s0; o16[WTPL + b2] = s1; o16[2 * WTPL + b2] = s2;
        } else if (mode == 4){
          o16[(size_t)r * ldd + c] = f2bf(v);
        } else if (mode == 5){
          of[((size_t)(r & 31) * 200 + (r >> 5)) * 80 + c] = v + aux[c];
        } else {
          of[(size_t)r * ldd + c] = v;
        }
      }
}

// ---------------- dedicated-checker barrier ----------------
// Arrival: per-block epoch STORE (64B stride, no RMW). Block 0's threads
// poll all 256 arrivals (one flag per thread), then publish one release
// word; all other blocks poll only the release word. All-wave vmcnt drain
// before arrival guarantees data stores reached MALL first.
__device__ __forceinline__ void gbar2(u32* arr, u32 ep, int tid, int blk){
  asm volatile("s_waitcnt vmcnt(0)" ::: "memory");
  __syncthreads();
  if (blk == 0){
    if (tid > 0 && tid < 256)
      while (aload32(&arr[tid * 16]) < ep) __builtin_amdgcn_s_sleep(1);
    __syncthreads();
    if (tid == 0) sigflag(&arr[4096], ep);
    __syncthreads();
  } else {
    if (tid == 0){
      sigflag(&arr[blk * 16], ep);
      while (aload32(&arr[4096]) < ep) __builtin_amdgcn_s_sleep(1);
      __builtin_amdgcn_sched_barrier(0);
    }
    __syncthreads();
  }
}

// ---------------- persistent scan kernel ----------------
struct CoopA {
  const us16 *wta, *wqt, *x2p, *kh, *kl;
  const float *mem, *vatt, *bperm;
  us16 *hpr;
  float *ucr, *sr, *qb, *cbuf, *hf32;
  u32 *arr;
};

__global__ void __launch_bounds__(512, 1) k_coop(CoopA a){
  __shared__ us16 khi[32][1024];
  __shared__ us16 klo[32][1024];
  __shared__ float zp[8][512];
  __shared__ float esc[32];
  __shared__ float rs_lds[32];

  // one-time invalidate: kill stale lines from a previous graph replay
  __builtin_amdgcn_fence(__ATOMIC_ACQUIRE, "agent");

  const int tid = threadIdx.x, blk = blockIdx.x;
  const int wv = tid >> 6, lane = tid & 63;
  const int r0 = lane & 15, kg = lane >> 4;
  const int cb_b = blk >> 3, cb_s0 = (blk & 7) * 32;   // phase-C identity
  const int colbase = blk * 16;
  const int u0 = lane * 16;

  // WTA slice pinned in registers for all 200 steps (96 VGPRs/thread).
  bf16x8 wr[8][3];
#pragma unroll
  for (int ks = 0; ks < 8; ++ks){
    const size_t wb = (size_t)(colbase + r0) * 2048 + (size_t)wv * 256 + ks * 32 + kg * 8;
#pragma unroll
    for (int p = 0; p < 3; ++p)
      wr[ks][p] = pin_reg(*(const bf16x8*)&a.wta[(size_t)p * WTPL + wb]);
  }

  // keys slice resident in LDS for all 200 steps
  {
    const size_t kbase = ((size_t)(cb_b * 256 + cb_s0)) * 1024;
    for (int i = tid; i < 4096; i += 512){
      int r = i >> 7, c8 = (i & 127) * 8;
      *(bf16x8*)&khi[r][c8] = *(const bf16x8*)&a.kh[kbase + (size_t)r * 1024 + c8];
      *(bf16x8*)&klo[r][c8] = *(const bf16x8*)&a.kl[kbase + (size_t)r * 1024 + c8];
    }
  }
  __syncthreads();

  u32 ep = 0;
  for (int t = 0; t < 200; ++t){
    // ===== phase A: z = [x|h|ctx] @ WTA (regs); gates -> h planes =====
    {
      if (tid < 32) rs_lds[tid] = 1.f / a.sr[(size_t)t * 32 + tid];
      __syncthreads();
      f32x4 acc0 = (f32x4){0.f,0.f,0.f,0.f}, acc1 = acc0;
#pragma unroll
      for (int ks = 0; ks < 8; ++ks){
        const int kf = wv * 256 + ks * 32 + kg * 8;
        bf16x8 w0 = wr[ks][0], w1 = wr[ks][1], w2 = wr[ks][2];
        bf16x8 a00, a01, a02, a10, a11, a12;
        if (wv < 2){
          const size_t xb0 = ((size_t)r0 * 200 + t) * 512 + kf;
          const size_t xb1 = ((size_t)(r0 + 16) * 200 + t) * 512 + kf;
          a00 = *(const bf16x8*)&a.x2p[xb0];
          a01 = *(const bf16x8*)&a.x2p[X2PL + xb0];
          a02 = *(const bf16x8*)&a.x2p[2 * X2PL + xb0];
          a10 = *(const bf16x8*)&a.x2p[xb1];
          a11 = *(const bf16x8*)&a.x2p[X2PL + xb1];
          a12 = *(const bf16x8*)&a.x2p[2 * X2PL + xb1];
        } else if (wv < 6){
          const int hk = kf - 512;
          const us16* hb = a.hpr + (size_t)t * 98304;
          a00 = ld16(&hb[(size_t)r0 * 1024 + hk]);
          a01 = ld16(&hb[32768 + (size_t)r0 * 1024 + hk]);
          a02 = ld16(&hb[65536 + (size_t)r0 * 1024 + hk]);
          a10 = ld16(&hb[(size_t)(r0 + 16) * 1024 + hk]);
          a11 = ld16(&hb[32768 + (size_t)(r0 + 16) * 1024 + hk]);
          a12 = ld16(&hb[65536 + (size_t)(r0 + 16) * 1024 + hk]);
        } else {
          const int ek = kf - 1536;
          const float* up = a.ucr + (size_t)t * 16384 + (size_t)r0 * 512 + ek;
          f32_frag3(up,        rs_lds[r0],      a00, a01, a02);
          f32_frag3(up + 8192, rs_lds[r0 + 16], a10, a11, a12);
        }
        acc0 = MFMA16(a00, w0, acc0, 0,0,0); acc0 = MFMA16(a00, w1, acc0, 0,0,0);
        acc0 = MFMA16(a01, w0, acc0, 0,0,0); acc0 = MFMA16(a00, w2, acc0, 0,0,0);
        acc0 = MFMA16(a01, w1, acc0, 0,0,0); acc0 = MFMA16(a02, w0, acc0, 0,0,0);
        acc1 = MFMA16(a10, w0, acc1, 0,0,0); acc1 = MFMA16(a10, w1, acc1, 0,0,0);
        acc1 = MFMA16(a11, w0, acc1, 0,0,0); acc1 = MFMA16(a10, w2, acc1, 0,0,0);
        acc1 = MFMA16(a11, w1, acc1, 0,0,0); acc1 = MFMA16(a12, w0, acc1, 0,0,0);
      }
#pragma unroll
      for (int i = 0; i < 4; ++i){
        zp[wv][(kg * 4 + i) * 16 + r0]      = acc0[i];
        zp[wv][(16 + kg * 4 + i) * 16 + r0] = acc1[i];
      }
      __syncthreads();
      float z = 0.f;
#pragma unroll
      for (int w = 0; w < 8; ++w) z += zp[w][tid];
      z += a.bperm[colbase + (tid & 15)];
      __syncthreads();
      zp[0][tid] = z;
      __syncthreads();
      if (tid < 128){
        int b = tid >> 2, ul = tid & 3, u = blk * 4 + ul;
        float zi = zp[0][b * 16 + ul * 4 + 0];
        float zf = zp[0][b * 16 + ul * 4 + 1];
        float zg = zp[0][b * 16 + ul * 4 + 2];
        float zo = zp[0][b * 16 + ul * 4 + 3];
        float co = a.cbuf[b * 1024 + u];
        float cn = sigf(zf) * co + sigf(zi) * tanh_fast(zg);
        float hn = sigf(zo) * tanh_fast(cn);
        a.cbuf[b * 1024 + u] = cn;                 // block-private
        a.hf32[b * 1024 + u] = hn;                 // plain; read post-dispatch
        us16 s0, s1, s2; split3(hn, s0, s1, s2);
        us16* hb = a.hpr + (size_t)(t + 1) * 98304;
        astore16(&hb[b * 1024 + u], s0);
        astore16(&hb[32768 + b * 1024 + u], s1);
        astore16(&hb[65536 + b * 1024 + u], s2);
      }
    }
    gbar2(a.arr, ++ep, tid, blk);

    // ===== phase B: q = h_new @ Wq (blocks 0..63; WQT cached, h planes) =====
    if (blk < 64){
      f32x4 acc0 = (f32x4){0.f,0.f,0.f,0.f}, acc1 = acc0;
#pragma unroll
      for (int ks = 0; ks < 4; ++ks){
        const int kf = wv * 128 + ks * 32 + kg * 8;
        const size_t wb = (size_t)(colbase + r0) * 1024 + kf;
        bf16x8 w0 = *(const bf16x8*)&a.wqt[wb];
        bf16x8 w1 = *(const bf16x8*)&a.wqt[WQPL + wb];
        bf16x8 w2 = *(const bf16x8*)&a.wqt[2 * WQPL + wb];
        const us16* hb = a.hpr + (size_t)(t + 1) * 98304;
        bf16x8 a00 = ld16(&hb[(size_t)r0 * 1024 + kf]);
        bf16x8 a01 = ld16(&hb[32768 + (size_t)r0 * 1024 + kf]);
        bf16x8 a02 = ld16(&hb[65536 + (size_t)r0 * 1024 + kf]);
        bf16x8 a10 = ld16(&hb[(size_t)(r0 + 16) * 1024 + kf]);
        bf16x8 a11 = ld16(&hb[32768 + (size_t)(r0 + 16) * 1024 + kf]);
        bf16x8 a12 = ld16(&hb[65536 + (size_t)(r0 + 16) * 1024 + kf]);
        acc0 = MFMA16(a00, w0, acc0, 0,0,0); acc0 = MFMA16(a00, w1, acc0, 0,0,0);
        acc0 = MFMA16(a01, w0, acc0, 0,0,0); acc0 = MFMA16(a00, w2, acc0, 0,0,0);
        acc0 = MFMA16(a01, w1, acc0, 0,0,0); acc0 = MFMA16(a02, w0, acc0, 0,0,0);
        acc1 = MFMA16(a10, w0, acc1, 0,0,0); acc1 = MFMA16(a10, w1, acc1, 0,0,0);
        acc1 = MFMA16(a11, w0, acc1, 0,0,0); acc1 = MFMA16(a10, w2, acc1, 0,0,0);
        acc1 = MFMA16(a11, w1, acc1, 0,0,0); acc1 = MFMA16(a12, w0, acc1, 0,0,0);
      }
#pragma unroll
      for (int i = 0; i < 4; ++i){
        zp[wv][(kg * 4 + i) * 16 + r0]      = acc0[i];
        zp[wv][(16 + kg * 4 + i) * 16 + r0] = acc1[i];
      }
      __syncthreads();
      float q = 0.f;
#pragma unroll
      for (int w = 0; w < 8; ++w) q += zp[w][tid];
      astoref(&a.qb[(size_t)(tid >> 4) * 1024 + colbase + (tid & 15)], q);
    }
    gbar2(a.arr, ++ep, tid, blk);

    // ===== phase C: score + exp + atomic ctx/sums (block = (b, s-slice32)) =====
    {
      float qv[16], vv[16];
      {
        const float* qp = a.qb + (size_t)cb_b * 1024 + u0;
        float4 q0 = aloadf4(qp), q1 = aloadf4(qp + 4);
        float4 q2 = aloadf4(qp + 8), q3 = aloadf4(qp + 12);
        qv[0]=q0.x; qv[1]=q0.y; qv[2]=q0.z; qv[3]=q0.w;
        qv[4]=q1.x; qv[5]=q1.y; qv[6]=q1.z; qv[7]=q1.w;
        qv[8]=q2.x; qv[9]=q2.y; qv[10]=q2.z; qv[11]=q2.w;
        qv[12]=q3.x; qv[13]=q3.y; qv[14]=q3.z; qv[15]=q3.w;
        float4 v0 = *(const float4*)(a.vatt + u0);
        float4 v1 = *(const float4*)(a.vatt + u0 + 4);
        float4 v2 = *(const float4*)(a.vatt + u0 + 8);
        float4 v3 = *(const float4*)(a.vatt + u0 + 12);
        vv[0]=v0.x; vv[1]=v0.y; vv[2]=v0.z; vv[3]=v0.w;
        vv[4]=v1.x; vv[5]=v1.y; vv[6]=v1.z; vv[7]=v1.w;
        vv[8]=v2.x; vv[9]=v2.y; vv[10]=v2.z; vv[11]=v2.w;
        vv[12]=v3.x; vv[13]=v3.y; vv[14]=v3.z; vv[15]=v3.w;
      }
#pragma unroll
      for (int m = 0; m < 4; ++m){
        const int sl = wv * 4 + m;
        bf16x8 h0 = *(const bf16x8*)&khi[sl][u0];
        bf16x8 h1 = *(const bf16x8*)&khi[sl][u0 + 8];
        bf16x8 l0 = *(const bf16x8*)&klo[sl][u0];
        bf16x8 l1 = *(const bf16x8*)&klo[sl][u0 + 8];
        float part = 0.f;
#pragma unroll
        for (int j = 0; j < 8; ++j){
          float kva = h2f((us16)h0[j]) + h2f((us16)l0[j]);
          part += vv[j] * tanh_fast(kva + qv[j]);
          float kvb = h2f((us16)h1[j]) + h2f((us16)l1[j]);
          part += vv[8 + j] * tanh_fast(kvb + qv[8 + j]);
        }
#pragma unroll
        for (int off = 32; off; off >>= 1) part += __shfl_xor(part, off);
        if (lane == 0) esc[sl] = __expf(part);   // max-free softmax (|score| small)
      }
      __syncthreads();
      if (tid == 0){
        float bs = 0.f;
#pragma unroll
        for (int i = 0; i < 32; ++i) bs += esc[i];
        aaddf(&a.sr[(size_t)(t + 1) * 32 + cb_b], bs);
      }
      {
        float ac0 = 0.f, ac1 = 0.f, ac2 = 0.f, ac3 = 0.f;
        const float* mrow = a.mem + ((size_t)(cb_b * 256 + cb_s0)) * 512 + tid;
#pragma unroll
        for (int j = 0; j < 32; j += 4){
          ac0 += esc[j]     * mrow[(size_t)j * 512];
          ac1 += esc[j + 1] * mrow[(size_t)(j + 1) * 512];
          ac2 += esc[j + 2] * mrow[(size_t)(j + 2) * 512];
          ac3 += esc[j + 3] * mrow[(size_t)(j + 3) * 512];
        }
        aaddf(&a.ucr[(size_t)(t + 1) * 16384 + cb_b * 512 + tid], (ac0 + ac1) + (ac2 + ac3));
      }
    }
    gbar2(a.arr, ++ep, tid, blk);
  }
}

// ---------------- hist reconstruction (post-loop, pure function of rolls) ----
__global__ void k_hist(const us16* __restrict__ hpr, const float* __restrict__ ucr,
                       const float* __restrict__ sr, us16* __restrict__ hist){
  int row = blockIdx.x;                 // 0..6431 = t*32 + b
  int t = row >> 5, b = row & 31;
  float rs = 1.f / sr[(size_t)t * 32 + b];
  for (int c = threadIdx.x; c < 1536; c += 256){
    us16 v;
    if (c < 1024) v = hpr[(size_t)t * 98304 + b * 1024 + c];       // plane0 = f2bf(h)
    else          v = f2bf(ucr[(size_t)t * 16384 + b * 512 + (c - 1024)] * rs);
    hist[(size_t)row * 1536 + c] = v;
  }
}

__global__ void k_copy_hc(const float* __restrict__ h, const float* __restrict__ c,
                          float* __restrict__ out){
  int i = blockIdx.x * 256 + threadIdx.x;
  if (i < 32768){
    out[512000 + i] = h[i];
    out[544768 + i] = c[i];
  }
}

// ---------------------------------------------------------------------------
extern "C" void kernel_launch(void* const* d_in, const int* in_sizes, int n_in,
                              void* d_out, int out_size, void* d_ws, size_t ws_size,
                              hipStream_t stream){
  const float* inputs = (const float*)d_in[0];
  const float* memory = (const float*)d_in[1];
  const float* W1     = (const float*)d_in[2];
  const float* b1     = (const float*)d_in[3];
  const float* W2     = (const float*)d_in[4];
  const float* b2     = (const float*)d_in[5];
  const float* Wx     = (const float*)d_in[6];
  const float* Wh     = (const float*)d_in[7];
  const float* b_lstm = (const float*)d_in[8];
  const float* Wm     = (const float*)d_in[9];
  const float* Wq     = (const float*)d_in[10];
  const float* v_att  = (const float*)d_in[11];
  const float* Wa     = (const float*)d_in[12];
  const float* Wp     = (const float*)d_in[13];
  const float* bp     = (const float*)d_in[14];
  float* out = (float*)d_out;
  char* ws = (char*)d_ws;
  if (ws_size < TOTAL_WS) return;

  us16* WTA    = (us16*)(ws + OFF_WTA);
  us16* WQT    = (us16*)(ws + OFF_WQT);
  us16* X2P    = (us16*)(ws + OFF_X2P);
  us16* KEYH   = (us16*)(ws + OFF_KEYH);
  float* X1    = (float*)(ws + OFF_X1);
  us16* HIST   = (us16*)(ws + OFF_HIST);
  us16* HPR    = (us16*)(ws + OFF_HPR);
  float* UCR   = (float*)(ws + OFF_UCR);
  float* SR    = (float*)(ws + OFF_SR);
  float* QB    = (float*)(ws + OFF_QB);
  float* CB    = (float*)(ws + OFF_CB);
  float* HF    = (float*)(ws + OFF_HF);
  us16* WAPN   = (us16*)(ws + OFF_WAPN);
  float* BPM   = (float*)(ws + OFF_BPERM);
  u32*  ARR    = (u32*)(ws + OFF_ARR);

  k_zero_init<<<256, 256, 0, stream>>>((u32*)HPR, UCR, SR, CB, ARR);
  k_bperm<<<16, 256, 0, stream>>>(b_lstm, BPM);
  k_transp3<<<dim3(32, 32), 256, 0, stream>>>(Wq, WQT, 1024, 1024, 1024, (long long)WQPL, 0);
  k_transp3<<<dim3(128, 16), 256, 0, stream>>>(Wx, WTA, 512, 4096, 2048, (long long)WTPL, 1);

  // fold: WTA rows 512..2047 = [Wh + WaTop@Wxb ; WaBot@Wxb], gate-permuted, triple-split
  k_gemm3<3,1,1><<<dim3(12, 64), 256, 0, stream>>>(Wa, Wx + (size_t)512 * 4096, WTA,
                                                   1536, 4096, 1024, 3, Wh, 0);
  // WapN = Wa @ Wp  [1536][80] bf16
  k_gemm3<3,1,1><<<dim3(12, 2), 256, 0, stream>>>(Wa, Wp, WAPN, 1536, 80, 1024, 4, nullptr, 80);
  // prenet 1: x1 = relu(inputs @ W1 + b1)  f32
  k_gemm3<3,1,1><<<dim3(50, 16), 256, 0, stream>>>(inputs, W1, X1, 6400, 1024, 80, 0, b1, 1024);
  // prenet 2: x2 = relu(x1 @ W2 + b2) -> triple planes
  k_gemm3<3,1,1><<<dim3(50, 8), 256, 0, stream>>>(X1, W2, X2P, 6400, 512, 1024, 1, b2, 512);
  // keys = memory @ Wm -> fp16 pair (overwrites X1 alias region; X1 dead now)
  k_gemm3<3,1,1><<<dim3(64, 16), 256, 0, stream>>>(memory, Wm, KEYH, 8192, 1024, 512, 2, nullptr, 1024);

  CoopA ca;
  ca.wta = WTA; ca.wqt = WQT; ca.x2p = X2P; ca.kh = KEYH; ca.kl = KEYH + WTPL;
  ca.mem = memory; ca.vatt = v_att; ca.bperm = BPM;
  ca.hpr = HPR; ca.ucr = UCR; ca.sr = SR;
  ca.qb = QB; ca.cbuf = CB; ca.hf32 = HF; ca.arr = ARR;
  void* args[] = {(void*)&ca};
  hipLaunchCooperativeKernel((const void*)k_coop, dim3(256), dim3(512), args, 0, stream);

  // rebuild hist from rolling buffers
  k_hist<<<6432, 256, 0, stream>>>(HPR, UCR, SR, HIST);
  // mel = hist[1..200] @ WapN + bp
  k_gemm3<1,0,0><<<dim3(50, 2), 256, 0, stream>>>(HIST + (size_t)32 * 1536, WAPN, out,
                                                  6400, 80, 1536, 5, bp, 0);
  // attn = hist[200] @ Wa
  k_gemm3<1,0,1><<<dim3(1, 16), 256, 0, stream>>>(HIST + (size_t)200 * 32 * 1536, Wa,
                                                  out + 577536, 32, 1024, 1536, 6, nullptr, 1024);
  k_copy_hc<<<128, 256, 0, stream>>>(HF, CB, out);
}

// Round 12
// 12575.402 us; speedup vs baseline: 1.1382x; 1.0052x over previous
//
#include <hip/hip_runtime.h>

// ---------------------------------------------------------------------------
// TacotronMelDecoder on MI355X (gfx950) — precision-hardened persistent scan.
// R12: rendezvous release de-contended. Old: all 255 blocks spin one MALL
// line (same-line reads serialize -> ~12us/rendezvous, the measured floor).
// New: block 0 gathers arrivals (256 distinct lines, one poller each) and
// publishes EIGHT group-release words (128B apart); each block polls only
// its group word (<=32 pollers/line). Phases identical to R11; q back to a
// rolling cached buffer (R8). 3 rendezvous/step.
// ---------------------------------------------------------------------------

typedef unsigned short us16;
typedef unsigned int u32;
typedef unsigned long long u64;
typedef __attribute__((ext_vector_type(8))) short bf16x8;
typedef __attribute__((ext_vector_type(4))) float f32x4;

#define MFMA16 __builtin_amdgcn_mfma_f32_16x16x32_bf16
#define AGT __HIP_MEMORY_SCOPE_AGENT

__device__ __forceinline__ us16 f2bf(float f){
  u32 u = __builtin_bit_cast(u32, f);
  u += 0x7fffu + ((u >> 16) & 1u);
  return (us16)(u >> 16);
}
__device__ __forceinline__ float bf2f(us16 h){
  return __builtin_bit_cast(float, ((u32)h) << 16);
}
__device__ __forceinline__ float h2f(us16 u){
  _Float16 h = __builtin_bit_cast(_Float16, u); return (float)h;
}
__device__ __forceinline__ us16 f2h(float f){
  _Float16 h = (_Float16)f; return __builtin_bit_cast(us16, h);
}
__device__ __forceinline__ void split3(float v, us16& s0, us16& s1, us16& s2){
  s0 = f2bf(v); float r = v - bf2f(s0);
  s1 = f2bf(r); r -= bf2f(s1);
  s2 = f2bf(r);
}
__device__ __forceinline__ float tanh_fast(float x){
  float e = __expf(-2.f * fmaxf(x, -40.f));
  return (1.f - e) / (1.f + e);
}
__device__ __forceinline__ float sigf(float x){
  return 1.f / (1.f + __expf(-x));
}

__device__ __forceinline__ u32 aload32(const u32* p){
  return __hip_atomic_load(p, __ATOMIC_RELAXED, AGT);
}
__device__ __forceinline__ void astore16(us16* p, us16 v){
  __hip_atomic_store(p, v, __ATOMIC_RELAXED, AGT);
}
__device__ __forceinline__ void astoref(float* p, float v){
  __hip_atomic_store(p, v, __ATOMIC_RELAXED, AGT);
}
__device__ __forceinline__ void sigflag(u32* p, u32 v){
  __hip_atomic_store(p, v, __ATOMIC_RELAXED, AGT);
}
__device__ __forceinline__ void aaddf(float* p, float v){
  __hip_atomic_fetch_add(p, v, __ATOMIC_RELAXED, AGT);
}
// plain cached 16B load (rolling addresses -> no staleness)
__device__ __forceinline__ bf16x8 ld16(const us16* p){
  return *(const bf16x8*)p;
}
// opacity: keep a loaded fragment in regs (non-rematerializable)
__device__ __forceinline__ bf16x8 pin_reg(bf16x8 v){
  f32x4 t = __builtin_bit_cast(f32x4, v);
  asm volatile("" : "+v"(t));
  return __builtin_bit_cast(bf16x8, t);
}
// 8 cached fp32 -> scaled triple-split bf16 fragments (ctx path)
__device__ __forceinline__ void f32_frag3(const float* p, float rs,
                                          bf16x8& f0, bf16x8& f1, bf16x8& f2){
  float4 t0 = *(const float4*)p;
  float4 t1 = *(const float4*)(p + 4);
  float tf[8] = {t0.x, t0.y, t0.z, t0.w, t1.x, t1.y, t1.z, t1.w};
#pragma unroll
  for (int i = 0; i < 8; ++i){
    float v = tf[i] * rs;
    us16 s0, s1, s2; split3(v, s0, s1, s2);
    f0[i] = (short)s0; f1[i] = (short)s1; f2[i] = (short)s2;
  }
}

// ---------------- workspace layout (bytes) ----------------
#define OFF_WTA    0ull            // 3 planes [4096][2048] bf16 (cols permuted u*4+gate)
#define OFF_WQT    50331648ull     // 3 planes [1024][1024] bf16 (Wq^T)
#define OFF_X2P    56623104ull     // 3 planes [32*200][512] bf16 (prenet out)
#define OFF_KEYH   76283904ull     // [8192][1024] fp16 hi
#define OFF_KEYL   93061120ull     // [8192][1024] fp16 lo
#define OFF_X1     76283904ull     // alias over KEYH/KEYL (dead before keys written)
#define OFF_HIST   109838336ull    // [201][32][1536] bf16 (built post-loop by k_hist)
#define OFF_HPR    129597440ull    // [201][3][32][1024] bf16 h planes (rolling)
#define OFF_UCR    169115648ull    // [201][32][512] f32 raw ctx sums (rolling, atomics)
#define OFF_SR     182288384ull    // [201][32] f32 softmax sums (rolling; slot0=1)
#define OFF_CB     182314112ull    // [32][1024] f32 c state (block-private)
#define OFF_HF     182445184ull    // [32][1024] f32 final h (plain)
#define OFF_WAPN   182576256ull    // [1536][80] bf16 (Wa@Wp natural)
#define OFF_BPERM  182822016ull    // [4096] f32
#define OFF_ARR    182838400ull    // arrivals 256x16 u32 + 8 release words @128B
#define OFF_QR     182859776ull    // [200][32][1024] f32 q (rolling)
#define TOTAL_WS   209084416ull

#define WTPL 8388608ull
#define WQPL 1048576ull
#define X2PL 3276800ull

// ---------------- init (re-run every launch: replay-safe) ----------------
__global__ void k_zero_init(u32* hpr0, float* ucr, float* sr, float* cbuf, u32* arr){
  u32 id = blockIdx.x * 256u + threadIdx.x;
  const u32 gs = 65536u;
  for (u32 i = id; i < 49152u;   i += gs) hpr0[i] = 0u;     // hp slot 0 (3 planes)
  for (u32 i = id; i < 3293184u; i += gs) ucr[i]  = 0.f;
  for (u32 i = id; i < 6432u;    i += gs) sr[i]   = (i < 32u) ? 1.f : 0.f;
  for (u32 i = id; i < 32768u;   i += gs) cbuf[i] = 0.f;
  for (u32 i = id; i < 5120u;    i += gs) arr[i]  = 0u;
}

__global__ void k_bperm(const float* __restrict__ bl, float* __restrict__ bpm){
  int c = blockIdx.x * 256 + threadIdx.x;
  if (c < 4096) bpm[((c & 1023) << 2) | (c >> 10)] = bl[c];
}

// ---------------- transpose f32 -> 3 bf16 planes (+optional gate perm) ----------------
__global__ void k_transp3(const float* __restrict__ src, us16* __restrict__ dst,
                          int srows, int scols, int ldd, long long pstride, int perm){
  __shared__ float tile[32][33];
  int bx = blockIdx.x * 32, by = blockIdx.y * 32;
  int tx = threadIdx.x & 31, ty = threadIdx.x >> 5;
#pragma unroll
  for (int i = 0; i < 4; ++i){
    int r = by + ty + i * 8, c = bx + tx;
    tile[ty + i * 8][tx] = (r < srows && c < scols) ? src[(size_t)r * scols + c] : 0.f;
  }
  __syncthreads();
#pragma unroll
  for (int i = 0; i < 4; ++i){
    int c = bx + ty + i * 8;
    int r = by + tx;
    if (c < scols && r < srows){
      int oc = perm ? (((c & 1023) << 2) | (c >> 10)) : c;
      float v = tile[tx][ty + i * 8];
      us16 s0, s1, s2; split3(v, s0, s1, s2);
      size_t base = (size_t)oc * ldd + r;
      dst[base] = s0; dst[(size_t)pstride + base] = s1; dst[2ull * pstride + base] = s2;
    }
  }
}

// ---------------- generic triple-split GEMM: C[M,N] = A[M,K] @ B[K,N] ----------------
// modes: 0 f32+bias+relu | 1 relu -> x2 triple planes | 2 keys fp16 pair
//        3 fold -> WTA planes (+Wh, perm) | 4 bf16 plain | 5 mel f32 | 6 f32 plain
template<int NP, int AF, int BF>
__global__ void __launch_bounds__(256)
k_gemm3(const void* __restrict__ Ap, const void* __restrict__ Bp, void* __restrict__ outp,
        int M, int N, int K, int mode, const float* __restrict__ aux, int ldd){
  __shared__ us16 At[NP][128][72];
  __shared__ us16 Bt[NP][64][72];
  const int tid = threadIdx.x, wv = tid >> 6, lane = tid & 63;
  const int r0 = lane & 15, kg = lane >> 4;
  const int rb = blockIdx.x * 128, cb = blockIdx.y * 64;
  f32x4 acc[2][4];
#pragma unroll
  for (int a = 0; a < 2; ++a)
#pragma unroll
    for (int b = 0; b < 4; ++b) acc[a][b] = (f32x4){0.f, 0.f, 0.f, 0.f};

  const int nkt = (K + 63) >> 6;
  for (int kt = 0; kt < nkt; ++kt){
    const int kb = kt * 64;
    for (int e = tid; e < 8192; e += 256){
      int r = e >> 6, k = e & 63, ga = rb + r, gk = kb + k;
      bool ok = (ga < M) && (gk < K);
      if constexpr (AF){
        float v = ok ? ((const float*)Ap)[(size_t)ga * K + gk] : 0.f;
        us16 s0, s1, s2; split3(v, s0, s1, s2);
        At[0][r][k] = s0;
        if constexpr (NP == 3){ At[1][r][k] = s1; At[2][r][k] = s2; }
      } else {
        At[0][r][k] = ok ? ((const us16*)Ap)[(size_t)ga * K + gk] : (us16)0;
      }
    }
    for (int e = tid; e < 4096; e += 256){
      int kr = e >> 6, c = e & 63, gk = kb + kr, gc = cb + c;
      bool ok = (gk < K) && (gc < N);
      if constexpr (BF){
        float v = ok ? ((const float*)Bp)[(size_t)gk * N + gc] : 0.f;
        us16 s0, s1, s2; split3(v, s0, s1, s2);
        Bt[0][c][kr] = s0;
        if constexpr (NP == 3){ Bt[1][c][kr] = s1; Bt[2][c][kr] = s2; }
      } else {
        Bt[0][c][kr] = ok ? ((const us16*)Bp)[(size_t)gk * N + gc] : (us16)0;
      }
    }
    __syncthreads();
#pragma unroll
    for (int kk = 0; kk < 64; kk += 32){
      bf16x8 af[NP][2];
#pragma unroll
      for (int p = 0; p < NP; ++p){
        af[p][0] = *(const bf16x8*)&At[p][wv * 32 + r0][kk + kg * 8];
        af[p][1] = *(const bf16x8*)&At[p][wv * 32 + 16 + r0][kk + kg * 8];
      }
#pragma unroll
      for (int cf = 0; cf < 4; ++cf){
        bf16x8 bv[NP];
#pragma unroll
        for (int p = 0; p < NP; ++p) bv[p] = *(const bf16x8*)&Bt[p][cf * 16 + r0][kk + kg * 8];
#pragma unroll
        for (int rf = 0; rf < 2; ++rf){
          acc[rf][cf] = MFMA16(af[0][rf], bv[0], acc[rf][cf], 0, 0, 0);
          if constexpr (NP == 3){
            acc[rf][cf] = MFMA16(af[0][rf], bv[1], acc[rf][cf], 0, 0, 0);
            acc[rf][cf] = MFMA16(af[1][rf], bv[0], acc[rf][cf], 0, 0, 0);
            acc[rf][cf] = MFMA16(af[0][rf], bv[2], acc[rf][cf], 0, 0, 0);
            acc[rf][cf] = MFMA16(af[1][rf], bv[1], acc[rf][cf], 0, 0, 0);
            acc[rf][cf] = MFMA16(af[2][rf], bv[0], acc[rf][cf], 0, 0, 0);
          }
        }
      }
    }
    __syncthreads();
  }
  us16* o16 = (us16*)outp; float* of = (float*)outp;
#pragma unroll
  for (int rf = 0; rf < 2; ++rf)
#pragma unroll
    for (int cf = 0; cf < 4; ++cf)
#pragma unroll
      for (int i = 0; i < 4; ++i){
        int r = rb + wv * 32 + rf * 16 + kg * 4 + i;
        int c = cb + cf * 16 + r0;
        if (r >= M || c >= N) continue;
        float v = acc[rf][cf][i];
        if (mode == 0){
          of[(size_t)r * ldd + c] = fmaxf(v + aux[c], 0.f);
        } else if (mode == 1){
          v = fmaxf(v + aux[c], 0.f);
          us16 s0, s1, s2; split3(v, s0, s1, s2);
          size_t b2 = (size_t)r * ldd + c;
          o16[b2] = s0; o16[X2PL + b2] = s1; o16[2 * X2PL + b2] = s2;
        } else if (mode == 2){
          us16 hh = f2h(v); float rem = v - h2f(hh); us16 hl = f2h(rem);
          size_t b2 = (size_t)r * 1024 + c;
          o16[b2] = hh; o16[WTPL + b2] = hl;
        } else if (mode == 3){
          float w = v + (r < 1024 ? aux[(size_t)r * 4096 + c] : 0.f);
          int pc = (c & 1023) * 4 + (c >> 10);
          us16 s0, s1, s2; split3(w, s0, s1, s2);
          size_t b2 = (size_t)pc * 2048 + 512 + r;
          o16[b2] = s0; o16[WTPL + b2] = s1; o16[2 * WTPL + b2] = s2;
        } else if (mode == 4){
          o16[(size_t)r * ldd + c] = f2bf(v);
        } else if (mode == 5){
          of[((size_t)(r & 31) * 200 + (r >> 5)) * 80 + c] = v + aux[c];
        } else {
          of[(size_t)r * ldd + c] = v;
        }
      }
}

// ---------------- de-contended rendezvous ----------------
// Arrival: per-block epoch STORE to a distinct 64B line. Block 0's threads
// poll the 256 arrival lines (one line per thread -> one poller per line),
// then publish EIGHT group-release words 128B apart; each other block polls
// only its group's word (<=32 pollers per line). All-wave vmcnt drain
// before arrival guarantees data stores reached MALL first.
__device__ __forceinline__ void gbar3(u32* arr, u32 ep, int tid, int blk){
  asm volatile("s_waitcnt vmcnt(0)" ::: "memory");
  __syncthreads();
  if (blk == 0){
    if (tid > 0 && tid < 256)
      while (aload32(&arr[tid * 16]) < ep) __builtin_amdgcn_s_sleep(2);
    __syncthreads();
    if (tid < 8) sigflag(&arr[4096 + tid * 32], ep);
    __syncthreads();
  } else {
    if (tid == 0){
      sigflag(&arr[blk * 16], ep);
      const int g = blk >> 5;
      while (aload32(&arr[4096 + g * 32]) < ep) __builtin_amdgcn_s_sleep(2);
      __builtin_amdgcn_sched_barrier(0);
    }
    __syncthreads();
  }
}

// ---------------- persistent scan kernel ----------------
struct CoopA {
  const us16 *wta, *wqt, *x2p, *kh, *kl;
  const float *mem, *vatt, *bperm;
  us16 *hpr;
  float *ucr, *sr, *qr, *cbuf, *hf32;
  u32 *arr;
};

__global__ void __launch_bounds__(512, 1) k_coop(CoopA a){
  __shared__ us16 khi[32][1024];
  __shared__ us16 klo[32][1024];
  __shared__ float zp[8][512];
  __shared__ float esc[32];
  __shared__ float rs_lds[32];

  // one-time invalidate: kill stale lines from a previous graph replay
  __builtin_amdgcn_fence(__ATOMIC_ACQUIRE, "agent");

  const int tid = threadIdx.x, blk = blockIdx.x;
  const int wv = tid >> 6, lane = tid & 63;
  const int r0 = lane & 15, kg = lane >> 4;
  const int cb_b = blk >> 3, cb_s0 = (blk & 7) * 32;   // phase-C identity
  const int colbase = blk * 16;
  const int u0 = lane * 16;

  // WTA slice pinned in registers for all 200 steps (96 VGPRs/thread).
  bf16x8 wr[8][3];
#pragma unroll
  for (int ks = 0; ks < 8; ++ks){
    const size_t wb = (size_t)(colbase + r0) * 2048 + (size_t)wv * 256 + ks * 32 + kg * 8;
#pragma unroll
    for (int p = 0; p < 3; ++p)
      wr[ks][p] = pin_reg(*(const bf16x8*)&a.wta[(size_t)p * WTPL + wb]);
  }

  // keys slice resident in LDS for all 200 steps
  {
    const size_t kbase = ((size_t)(cb_b * 256 + cb_s0)) * 1024;
    for (int i = tid; i < 4096; i += 512){
      int r = i >> 7, c8 = (i & 127) * 8;
      *(bf16x8*)&khi[r][c8] = *(const bf16x8*)&a.kh[kbase + (size_t)r * 1024 + c8];
      *(bf16x8*)&klo[r][c8] = *(const bf16x8*)&a.kl[kbase + (size_t)r * 1024 + c8];
    }
  }
  __syncthreads();

  u32 ep = 0;
  for (int t = 0; t < 200; ++t){
    // ===== phase A: z = [x|h|ctx] @ WTA (regs); gates -> h planes =====
    {
      if (tid < 32) rs_lds[tid] = 1.f / a.sr[(size_t)t * 32 + tid];
      __syncthreads();
      f32x4 acc0 = (f32x4){0.f,0.f,0.f,0.f}, acc1 = acc0;
#pragma unroll
      for (int ks = 0; ks < 8; ++ks){
        const int kf = wv * 256 + ks * 32 + kg * 8;
        bf16x8 w0 = wr[ks][0], w1 = wr[ks][1], w2 = wr[ks][2];
        bf16x8 a00, a01, a02, a10, a11, a12;
        if (wv < 2){
          const size_t xb0 = ((size_t)r0 * 200 + t) * 512 + kf;
          const size_t xb1 = ((size_t)(r0 + 16) * 200 + t) * 512 + kf;
          a00 = *(const bf16x8*)&a.x2p[xb0];
          a01 = *(const bf16x8*)&a.x2p[X2PL + xb0];
          a02 = *(const bf16x8*)&a.x2p[2 * X2PL + xb0];
          a10 = *(const bf16x8*)&a.x2p[xb1];
          a11 = *(const bf16x8*)&a.x2p[X2PL + xb1];
          a12 = *(const bf16x8*)&a.x2p[2 * X2PL + xb1];
        } else if (wv < 6){
          const int hk = kf - 512;
          const us16* hb = a.hpr + (size_t)t * 98304;
          a00 = ld16(&hb[(size_t)r0 * 1024 + hk]);
          a01 = ld16(&hb[32768 + (size_t)r0 * 1024 + hk]);
          a02 = ld16(&hb[65536 + (size_t)r0 * 1024 + hk]);
          a10 = ld16(&hb[(size_t)(r0 + 16) * 1024 + hk]);
          a11 = ld16(&hb[32768 + (size_t)(r0 + 16) * 1024 + hk]);
          a12 = ld16(&hb[65536 + (size_t)(r0 + 16) * 1024 + hk]);
        } else {
          const int ek = kf - 1536;
          const float* up = a.ucr + (size_t)t * 16384 + (size_t)r0 * 512 + ek;
          f32_frag3(up,        rs_lds[r0],      a00, a01, a02);
          f32_frag3(up + 8192, rs_lds[r0 + 16], a10, a11, a12);
        }
        acc0 = MFMA16(a00, w0, acc0, 0,0,0); acc0 = MFMA16(a00, w1, acc0, 0,0,0);
        acc0 = MFMA16(a01, w0, acc0, 0,0,0); acc0 = MFMA16(a00, w2, acc0, 0,0,0);
        acc0 = MFMA16(a01, w1, acc0, 0,0,0); acc0 = MFMA16(a02, w0, acc0, 0,0,0);
        acc1 = MFMA16(a10, w0, acc1, 0,0,0); acc1 = MFMA16(a10, w1, acc1, 0,0,0);
        acc1 = MFMA16(a11, w0, acc1, 0,0,0); acc1 = MFMA16(a10, w2, acc1, 0,0,0);
        acc1 = MFMA16(a11, w1, acc1, 0,0,0); acc1 = MFMA16(a12, w0, acc1, 0,0,0);
      }
#pragma unroll
      for (int i = 0; i < 4; ++i){
        zp[wv][(kg * 4 + i) * 16 + r0]      = acc0[i];
        zp[wv][(16 + kg * 4 + i) * 16 + r0] = acc1[i];
      }
      __syncthreads();
      float z = 0.f;
#pragma unroll
      for (int w = 0; w < 8; ++w) z += zp[w][tid];
      z += a.bperm[colbase + (tid & 15)];
      __syncthreads();
      zp[0][tid] = z;
      __syncthreads();
      if (tid < 128){
        int b = tid >> 2, ul = tid & 3, u = blk * 4 + ul;
        float zi = zp[0][b * 16 + ul * 4 + 0];
        float zf = zp[0][b * 16 + ul * 4 + 1];
        float zg = zp[0][b * 16 + ul * 4 + 2];
        float zo = zp[0][b * 16 + ul * 4 + 3];
        float co = a.cbuf[b * 1024 + u];
        float cn = sigf(zf) * co + sigf(zi) * tanh_fast(zg);
        float hn = sigf(zo) * tanh_fast(cn);
        a.cbuf[b * 1024 + u] = cn;                 // block-private
        a.hf32[b * 1024 + u] = hn;                 // plain; read post-dispatch
        us16 s0, s1, s2; split3(hn, s0, s1, s2);
        us16* hb = a.hpr + (size_t)(t + 1) * 98304;
        astore16(&hb[b * 1024 + u], s0);
        astore16(&hb[32768 + b * 1024 + u], s1);
        astore16(&hb[65536 + b * 1024 + u], s2);
      }
    }
    gbar3(a.arr, ++ep, tid, blk);

    // ===== phase B: q = h_new @ Wq (blocks 0..63; WQT cached, h planes) =====
    if (blk < 64){
      f32x4 acc0 = (f32x4){0.f,0.f,0.f,0.f}, acc1 = acc0;
#pragma unroll
      for (int ks = 0; ks < 4; ++ks){
        const int kf = wv * 128 + ks * 32 + kg * 8;
        const size_t wb = (size_t)(colbase + r0) * 1024 + kf;
        bf16x8 w0 = *(const bf16x8*)&a.wqt[wb];
        bf16x8 w1 = *(const bf16x8*)&a.wqt[WQPL + wb];
        bf16x8 w2 = *(const bf16x8*)&a.wqt[2 * WQPL + wb];
        const us16* hb = a.hpr + (size_t)(t + 1) * 98304;
        bf16x8 a00 = ld16(&hb[(size_t)r0 * 1024 + kf]);
        bf16x8 a01 = ld16(&hb[32768 + (size_t)r0 * 1024 + kf]);
        bf16x8 a02 = ld16(&hb[65536 + (size_t)r0 * 1024 + kf]);
        bf16x8 a10 = ld16(&hb[(size_t)(r0 + 16) * 1024 + kf]);
        bf16x8 a11 = ld16(&hb[32768 + (size_t)(r0 + 16) * 1024 + kf]);
        bf16x8 a12 = ld16(&hb[65536 + (size_t)(r0 + 16) * 1024 + kf]);
        acc0 = MFMA16(a00, w0, acc0, 0,0,0); acc0 = MFMA16(a00, w1, acc0, 0,0,0);
        acc0 = MFMA16(a01, w0, acc0, 0,0,0); acc0 = MFMA16(a00, w2, acc0, 0,0,0);
        acc0 = MFMA16(a01, w1, acc0, 0,0,0); acc0 = MFMA16(a02, w0, acc0, 0,0,0);
        acc1 = MFMA16(a10, w0, acc1, 0,0,0); acc1 = MFMA16(a10, w1, acc1, 0,0,0);
        acc1 = MFMA16(a11, w0, acc1, 0,0,0); acc1 = MFMA16(a10, w2, acc1, 0,0,0);
        acc1 = MFMA16(a11, w1, acc1, 0,0,0); acc1 = MFMA16(a12, w0, acc1, 0,0,0);
      }
#pragma unroll
      for (int i = 0; i < 4; ++i){
        zp[wv][(kg * 4 + i) * 16 + r0]      = acc0[i];
        zp[wv][(16 + kg * 4 + i) * 16 + r0] = acc1[i];
      }
      __syncthreads();
      float q = 0.f;
#pragma unroll
      for (int w = 0; w < 8; ++w) q += zp[w][tid];
      astoref(&a.qr[(size_t)t * 32768 + (size_t)(tid >> 4) * 1024 + colbase + (tid & 15)], q);
    }
    gbar3(a.arr, ++ep, tid, blk);

    // ===== phase C: score + exp + atomic ctx/sums (block = (b, s-slice32)) =====
    {
      float qv[16], vv[16];
      {
        const float* qp = a.qr + (size_t)t * 32768 + (size_t)cb_b * 1024 + u0;
        float4 q0 = *(const float4*)qp;
        float4 q1 = *(const float4*)(qp + 4);
        float4 q2 = *(const float4*)(qp + 8);
        float4 q3 = *(const float4*)(qp + 12);
        qv[0]=q0.x; qv[1]=q0.y; qv[2]=q0.z; qv[3]=q0.w;
        qv[4]=q1.x; qv[5]=q1.y; qv[6]=q1.z; qv[7]=q1.w;
        qv[8]=q2.x; qv[9]=q2.y; qv[10]=q2.z; qv[11]=q2.w;
        qv[12]=q3.x; qv[13]=q3.y; qv[14]=q3.z; qv[15]=q3.w;
        float4 v0 = *(const float4*)(a.vatt + u0);
        float4 v1 = *(const float4*)(a.vatt + u0 + 4);
        float4 v2 = *(const float4*)(a.vatt + u0 + 8);
        float4 v3 = *(const float4*)(a.vatt + u0 + 12);
        vv[0]=v0.x; vv[1]=v0.y; vv[2]=v0.z; vv[3]=v0.w;
        vv[4]=v1.x; vv[5]=v1.y; vv[6]=v1.z; vv[7]=v1.w;
        vv[8]=v2.x; vv[9]=v2.y; vv[10]=v2.z; vv[11]=v2.w;
        vv[12]=v3.x; vv[13]=v3.y; vv[14]=v3.z; vv[15]=v3.w;
      }
#pragma unroll
      for (int m = 0; m < 4; ++m){
        const int sl = wv * 4 + m;
        bf16x8 h0 = *(const bf16x8*)&khi[sl][u0];
        bf16x8 h1 = *(const bf16x8*)&khi[sl][u0 + 8];
        bf16x8 l0 = *(const bf16x8*)&klo[sl][u0];
        bf16x8 l1 = *(const bf16x8*)&klo[sl][u0 + 8];
        float part = 0.f;
#pragma unroll
        for (int j = 0; j < 8; ++j){
          float kva = h2f((us16)h0[j]) + h2f((us16)l0[j]);
          part += vv[j] * tanh_fast(kva + qv[j]);
          float kvb = h2f((us16)h1[j]) + h2f((us16)l1[j]);
          part += vv[8 + j] * tanh_fast(kvb + qv[8 + j]);
        }
#pragma unroll
        for (int off = 32; off; off >>= 1) part += __shfl_xor(part, off);
        if (lane == 0) esc[sl] = __expf(part);   // max-free softmax (|score| small)
      }
      __syncthreads();
      if (tid == 0){
        float bs = 0.f;
#pragma unroll
        for (int i = 0; i < 32; ++i) bs += esc[i];
        aaddf(&a.sr[(size_t)(t + 1) * 32 + cb_b], bs);
      }
      {
        float ac0 = 0.f, ac1 = 0.f, ac2 = 0.f, ac3 = 0.f;
        const float* mrow = a.mem + ((size_t)(cb_b * 256 + cb_s0)) * 512 + tid;
#pragma unroll
        for (int j = 0; j < 32; j += 4){
          ac0 += esc[j]     * mrow[(size_t)j * 512];
          ac1 += esc[j + 1] * mrow[(size_t)(j + 1) * 512];
          ac2 += esc[j + 2] * mrow[(size_t)(j + 2) * 512];
          ac3 += esc[j + 3] * mrow[(size_t)(j + 3) * 512];
        }
        aaddf(&a.ucr[(size_t)(t + 1) * 16384 + cb_b * 512 + tid], (ac0 + ac1) + (ac2 + ac3));
      }
    }
    gbar3(a.arr, ++ep, tid, blk);
  }
}

// ---------------- hist reconstruction (post-loop, pure function of rolls) ----
__global__ void k_hist(const us16* __restrict__ hpr, const float* __restrict__ ucr,
                       const float* __restrict__ sr, us16* __restrict__ hist){
  int row = blockIdx.x;                 // 0..6431 = t*32 + b
  int t = row >> 5, b = row & 31;
  float rs = 1.f / sr[(size_t)t * 32 + b];
  for (int c = threadIdx.x; c < 1536; c += 256){
    us16 v;
    if (c < 1024) v = hpr[(size_t)t * 98304 + b * 1024 + c];       // plane0 = f2bf(h)
    else          v = f2bf(ucr[(size_t)t * 16384 + b * 512 + (c - 1024)] * rs);
    hist[(size_t)row * 1536 + c] = v;
  }
}

__global__ void k_copy_hc(const float* __restrict__ h, const float* __restrict__ c,
                          float* __restrict__ out){
  int i = blockIdx.x * 256 + threadIdx.x;
  if (i < 32768){
    out[512000 + i] = h[i];
    out[544768 + i] = c[i];
  }
}

// ---------------------------------------------------------------------------
extern "C" void kernel_launch(void* const* d_in, const int* in_sizes, int n_in,
                              void* d_out, int out_size, void* d_ws, size_t ws_size,
                              hipStream_t stream){
  const float* inputs = (const float*)d_in[0];
  const float* memory = (const float*)d_in[1];
  const float* W1     = (const float*)d_in[2];
  const float* b1     = (const float*)d_in[3];
  const float* W2     = (const float*)d_in[4];
  const float* b2     = (const float*)d_in[5];
  const float* Wx     = (const float*)d_in[6];
  const float* Wh     = (const float*)d_in[7];
  const float* b_lstm = (const float*)d_in[8];
  const float* Wm     = (const float*)d_in[9];
  const float* Wq     = (const float*)d_in[10];
  const float* v_att  = (const float*)d_in[11];
  const float* Wa     = (const float*)d_in[12];
  const float* Wp     = (const float*)d_in[13];
  const float* bp     = (const float*)d_in[14];
  float* out = (float*)d_out;
  char* ws = (char*)d_ws;
  if (ws_size < TOTAL_WS) return;

  us16* WTA    = (us16*)(ws + OFF_WTA);
  us16* WQT    = (us16*)(ws + OFF_WQT);
  us16* X2P    = (us16*)(ws + OFF_X2P);
  us16* KEYH   = (us16*)(ws + OFF_KEYH);
  float* X1    = (float*)(ws + OFF_X1);
  us16* HIST   = (us16*)(ws + OFF_HIST);
  us16* HPR    = (us16*)(ws + OFF_HPR);
  float* UCR   = (float*)(ws + OFF_UCR);
  float* SR    = (float*)(ws + OFF_SR);
  float* QR    = (float*)(ws + OFF_QR);
  float* CB    = (float*)(ws + OFF_CB);
  float* HF    = (float*)(ws + OFF_HF);
  us16* WAPN   = (us16*)(ws + OFF_WAPN);
  float* BPM   = (float*)(ws + OFF_BPERM);
  u32*  ARR    = (u32*)(ws + OFF_ARR);

  k_zero_init<<<256, 256, 0, stream>>>((u32*)HPR, UCR, SR, CB, ARR);
  k_bperm<<<16, 256, 0, stream>>>(b_lstm, BPM);
  k_transp3<<<dim3(32, 32), 256, 0, stream>>>(Wq, WQT, 1024, 1024, 1024, (long long)WQPL, 0);
  k_transp3<<<dim3(128, 16), 256, 0, stream>>>(Wx, WTA, 512, 4096, 2048, (long long)WTPL, 1);

  // fold: WTA rows 512..2047 = [Wh + WaTop@Wxb ; WaBot@Wxb], gate-permuted, triple-split
  k_gemm3<3,1,1><<<dim3(12, 64), 256, 0, stream>>>(Wa, Wx + (size_t)512 * 4096, WTA,
                                                   1536, 4096, 1024, 3, Wh, 0);
  // WapN = Wa @ Wp  [1536][80] bf16
  k_gemm3<3,1,1><<<dim3(12, 2), 256, 0, stream>>>(Wa, Wp, WAPN, 1536, 80, 1024, 4, nullptr, 80);
  // prenet 1: x1 = relu(inputs @ W1 + b1)  f32
  k_gemm3<3,1,1><<<dim3(50, 16), 256, 0, stream>>>(inputs, W1, X1, 6400, 1024, 80, 0, b1, 1024);
  // prenet 2: x2 = relu(x1 @ W2 + b2) -> triple planes
  k_gemm3<3,1,1><<<dim3(50, 8), 256, 0, stream>>>(X1, W2, X2P, 6400, 512, 1024, 1, b2, 512);
  // keys = memory @ Wm -> fp16 pair (overwrites X1 alias region; X1 dead now)
  k_gemm3<3,1,1><<<dim3(64, 16), 256, 0, stream>>>(memory, Wm, KEYH, 8192, 1024, 512, 2, nullptr, 1024);

  CoopA ca;
  ca.wta = WTA; ca.wqt = WQT; ca.x2p = X2P; ca.kh = KEYH; ca.kl = KEYH + WTPL;
  ca.mem = memory; ca.vatt = v_att; ca.bperm = BPM;
  ca.hpr = HPR; ca.ucr = UCR; ca.sr = SR;
  ca.qr = QR; ca.cbuf = CB; ca.hf32 = HF; ca.arr = ARR;
  void* args[] = {(void*)&ca};
  hipLaunchCooperativeKernel((const void*)k_coop, dim3(256), dim3(512), args, 0, stream);

  // rebuild hist from rolling buffers
  k_hist<<<6432, 256, 0, stream>>>(HPR, UCR, SR, HIST);
  // mel = hist[1..200] @ WapN + bp
  k_gemm3<1,0,0><<<dim3(50, 2), 256, 0, stream>>>(HIST + (size_t)32 * 1536, WAPN, out,
                                                  6400, 80, 1536, 5, bp, 0);
  // attn = hist[200] @ Wa
  k_gemm3<1,0,1><<<dim3(1, 16), 256, 0, stream>>>(HIST + (size_t)200 * 32 * 1536, Wa,
                                                  out + 577536, 32, 1024, 1536, 6, nullptr, 1024);
  k_copy_hc<<<128, 256, 0, stream>>>(HF, CB, out);
}

// Round 13
// 11846.778 us; speedup vs baseline: 1.2082x; 1.0615x over previous
//
#include <hip/hip_runtime.h>

// ---------------------------------------------------------------------------
// TacotronMelDecoder on MI355X (gfx950) — precision-hardened persistent scan.
// R13: batch-split software pipeline. B=32 rows = 32 independent chains;
// split G0(b0-15)/G1(b16-31). 6 half-phases/step with split ARRIVE/WAIT
// (two-level last-arriver-release, no checker): every G0 rendezvous hides
// under G1 compute and vice versa. B0 on blocks 0-63, B1 on 64-127 (64-
// arriver sets); C remapped to 16b x 16slices (all blocks active each half).
// Rolling write-once buffers keep cached cross-block reads staleness-free.
// ---------------------------------------------------------------------------

typedef unsigned short us16;
typedef unsigned int u32;
typedef unsigned long long u64;
typedef __attribute__((ext_vector_type(8))) short bf16x8;
typedef __attribute__((ext_vector_type(4))) float f32x4;

#define MFMA16 __builtin_amdgcn_mfma_f32_16x16x32_bf16
#define AGT __HIP_MEMORY_SCOPE_AGENT

__device__ __forceinline__ us16 f2bf(float f){
  u32 u = __builtin_bit_cast(u32, f);
  u += 0x7fffu + ((u >> 16) & 1u);
  return (us16)(u >> 16);
}
__device__ __forceinline__ float bf2f(us16 h){
  return __builtin_bit_cast(float, ((u32)h) << 16);
}
__device__ __forceinline__ float h2f(us16 u){
  _Float16 h = __builtin_bit_cast(_Float16, u); return (float)h;
}
__device__ __forceinline__ us16 f2h(float f){
  _Float16 h = (_Float16)f; return __builtin_bit_cast(us16, h);
}
__device__ __forceinline__ void split3(float v, us16& s0, us16& s1, us16& s2){
  s0 = f2bf(v); float r = v - bf2f(s0);
  s1 = f2bf(r); r -= bf2f(s1);
  s2 = f2bf(r);
}
__device__ __forceinline__ float tanh_fast(float x){
  float e = __expf(-2.f * fmaxf(x, -40.f));
  return (1.f - e) / (1.f + e);
}
__device__ __forceinline__ float sigf(float x){
  return 1.f / (1.f + __expf(-x));
}

__device__ __forceinline__ u32 aload32(const u32* p){
  return __hip_atomic_load(p, __ATOMIC_RELAXED, AGT);
}
__device__ __forceinline__ void astore16(us16* p, us16 v){
  __hip_atomic_store(p, v, __ATOMIC_RELAXED, AGT);
}
__device__ __forceinline__ void astoref(float* p, float v){
  __hip_atomic_store(p, v, __ATOMIC_RELAXED, AGT);
}
__device__ __forceinline__ void sigflag(u32* p, u32 v){
  __hip_atomic_store(p, v, __ATOMIC_RELAXED, AGT);
}
__device__ __forceinline__ void aaddf(float* p, float v){
  __hip_atomic_fetch_add(p, v, __ATOMIC_RELAXED, AGT);
}
__device__ __forceinline__ bf16x8 ld16(const us16* p){
  return *(const bf16x8*)p;
}
// opacity: keep a loaded fragment in regs (non-rematerializable)
__device__ __forceinline__ bf16x8 pin_reg(bf16x8 v){
  f32x4 t = __builtin_bit_cast(f32x4, v);
  asm volatile("" : "+v"(t));
  return __builtin_bit_cast(bf16x8, t);
}
// 8 cached fp32 -> scaled triple-split bf16 fragments (ctx path)
__device__ __forceinline__ void f32_frag3(const float* p, float rs,
                                          bf16x8& f0, bf16x8& f1, bf16x8& f2){
  float4 t0 = *(const float4*)p;
  float4 t1 = *(const float4*)(p + 4);
  float tf[8] = {t0.x, t0.y, t0.z, t0.w, t1.x, t1.y, t1.z, t1.w};
#pragma unroll
  for (int i = 0; i < 8; ++i){
    float v = tf[i] * rs;
    us16 s0, s1, s2; split3(v, s0, s1, s2);
    f0[i] = (short)s0; f1[i] = (short)s1; f2[i] = (short)s2;
  }
}

// ---------------- workspace layout (bytes) ----------------
#define OFF_WTA    0ull            // 3 planes [4096][2048] bf16 (cols permuted u*4+gate)
#define OFF_WQT    50331648ull     // 3 planes [1024][1024] bf16 (Wq^T)
#define OFF_X2P    56623104ull     // 3 planes [32*200][512] bf16 (prenet out)
#define OFF_KEYH   76283904ull     // [8192][1024] fp16 hi
#define OFF_KEYL   93061120ull     // [8192][1024] fp16 lo
#define OFF_X1     76283904ull     // alias over KEYH/KEYL (dead before keys written)
#define OFF_HIST   109838336ull    // [201][32][1536] bf16 (built post-loop by k_hist)
#define OFF_HPR    129597440ull    // [201][3][32][1024] bf16 h planes (rolling)
#define OFF_UCR    169115648ull    // [201][32][512] f32 raw ctx sums (rolling, atomics)
#define OFF_SR     182288384ull    // [201][32] f32 softmax sums (rolling; slot0=1)
#define OFF_CB     182314112ull    // [32][1024] f32 c state (block-private)
#define OFF_HF     182445184ull    // [32][1024] f32 final h (plain)
#define OFF_WAPN   182576256ull    // [1536][80] bf16 (Wa@Wp natural)
#define OFF_BPERM  182822016ull    // [4096] f32
#define OFF_ARR    182838400ull    // sync: 6 sets x 8 grp cnt + roots + releases
#define OFF_QR     182870016ull    // [200][32][1024] f32 q (rolling)
#define TOTAL_WS   209094656ull

#define WTPL 8388608ull
#define WQPL 1048576ull
#define X2PL 3276800ull

// sync sets
#define SA0 0
#define SA1 1
#define SB0 2
#define SB1 3
#define SC0 4
#define SC1 5

// ---------------- init (re-run every launch: replay-safe) ----------------
__global__ void k_zero_init(u32* hpr0, float* ucr, float* sr, float* cbuf, u32* arr){
  u32 id = blockIdx.x * 256u + threadIdx.x;
  const u32 gs = 65536u;
  for (u32 i = id; i < 49152u;   i += gs) hpr0[i] = 0u;     // hp slot 0 (3 planes)
  for (u32 i = id; i < 3293184u; i += gs) ucr[i]  = 0.f;
  for (u32 i = id; i < 6432u;    i += gs) sr[i]   = (i < 32u) ? 1.f : 0.f;
  for (u32 i = id; i < 32768u;   i += gs) cbuf[i] = 0.f;
  for (u32 i = id; i < 2048u;    i += gs) arr[i]  = 0u;
}

__global__ void k_bperm(const float* __restrict__ bl, float* __restrict__ bpm){
  int c = blockIdx.x * 256 + threadIdx.x;
  if (c < 4096) bpm[((c & 1023) << 2) | (c >> 10)] = bl[c];
}

// ---------------- transpose f32 -> 3 bf16 planes (+optional gate perm) ----------------
__global__ void k_transp3(const float* __restrict__ src, us16* __restrict__ dst,
                          int srows, int scols, int ldd, long long pstride, int perm){
  __shared__ float tile[32][33];
  int bx = blockIdx.x * 32, by = blockIdx.y * 32;
  int tx = threadIdx.x & 31, ty = threadIdx.x >> 5;
#pragma unroll
  for (int i = 0; i < 4; ++i){
    int r = by + ty + i * 8, c = bx + tx;
    tile[ty + i * 8][tx] = (r < srows && c < scols) ? src[(size_t)r * scols + c] : 0.f;
  }
  __syncthreads();
#pragma unroll
  for (int i = 0; i < 4; ++i){
    int c = bx + ty + i * 8;
    int r = by + tx;
    if (c < scols && r < srows){
      int oc = perm ? (((c & 1023) << 2) | (c >> 10)) : c;
      float v = tile[tx][ty + i * 8];
      us16 s0, s1, s2; split3(v, s0, s1, s2);
      size_t base = (size_t)oc * ldd + r;
      dst[base] = s0; dst[(size_t)pstride + base] = s1; dst[2ull * pstride + base] = s2;
    }
  }
}

// ---------------- generic triple-split GEMM: C[M,N] = A[M,K] @ B[K,N] ----------------
// modes: 0 f32+bias+relu | 1 relu -> x2 triple planes | 2 keys fp16 pair
//        3 fold -> WTA planes (+Wh, perm) | 4 bf16 plain | 5 mel f32 | 6 f32 plain
template<int NP, int AF, int BF>
__global__ void __launch_bounds__(256)
k_gemm3(const void* __restrict__ Ap, const void* __restrict__ Bp, void* __restrict__ outp,
        int M, int N, int K, int mode, const float* __restrict__ aux, int ldd){
  __shared__ us16 At[NP][128][72];
  __shared__ us16 Bt[NP][64][72];
  const int tid = threadIdx.x, wv = tid >> 6, lane = tid & 63;
  const int r0 = lane & 15, kg = lane >> 4;
  const int rb = blockIdx.x * 128, cb = blockIdx.y * 64;
  f32x4 acc[2][4];
#pragma unroll
  for (int a = 0; a < 2; ++a)
#pragma unroll
    for (int b = 0; b < 4; ++b) acc[a][b] = (f32x4){0.f, 0.f, 0.f, 0.f};

  const int nkt = (K + 63) >> 6;
  for (int kt = 0; kt < nkt; ++kt){
    const int kb = kt * 64;
    for (int e = tid; e < 8192; e += 256){
      int r = e >> 6, k = e & 63, ga = rb + r, gk = kb + k;
      bool ok = (ga < M) && (gk < K);
      if constexpr (AF){
        float v = ok ? ((const float*)Ap)[(size_t)ga * K + gk] : 0.f;
        us16 s0, s1, s2; split3(v, s0, s1, s2);
        At[0][r][k] = s0;
        if constexpr (NP == 3){ At[1][r][k] = s1; At[2][r][k] = s2; }
      } else {
        At[0][r][k] = ok ? ((const us16*)Ap)[(size_t)ga * K + gk] : (us16)0;
      }
    }
    for (int e = tid; e < 4096; e += 256){
      int kr = e >> 6, c = e & 63, gk = kb + kr, gc = cb + c;
      bool ok = (gk < K) && (gc < N);
      if constexpr (BF){
        float v = ok ? ((const float*)Bp)[(size_t)gk * N + gc] : 0.f;
        us16 s0, s1, s2; split3(v, s0, s1, s2);
        Bt[0][c][kr] = s0;
        if constexpr (NP == 3){ Bt[1][c][kr] = s1; Bt[2][c][kr] = s2; }
      } else {
        Bt[0][c][kr] = ok ? ((const us16*)Bp)[(size_t)gk * N + gc] : (us16)0;
      }
    }
    __syncthreads();
#pragma unroll
    for (int kk = 0; kk < 64; kk += 32){
      bf16x8 af[NP][2];
#pragma unroll
      for (int p = 0; p < NP; ++p){
        af[p][0] = *(const bf16x8*)&At[p][wv * 32 + r0][kk + kg * 8];
        af[p][1] = *(const bf16x8*)&At[p][wv * 32 + 16 + r0][kk + kg * 8];
      }
#pragma unroll
      for (int cf = 0; cf < 4; ++cf){
        bf16x8 bv[NP];
#pragma unroll
        for (int p = 0; p < NP; ++p) bv[p] = *(const bf16x8*)&Bt[p][cf * 16 + r0][kk + kg * 8];
#pragma unroll
        for (int rf = 0; rf < 2; ++rf){
          acc[rf][cf] = MFMA16(af[0][rf], bv[0], acc[rf][cf], 0, 0, 0);
          if constexpr (NP == 3){
            acc[rf][cf] = MFMA16(af[0][rf], bv[1], acc[rf][cf], 0, 0, 0);
            acc[rf][cf] = MFMA16(af[1][rf], bv[0], acc[rf][cf], 0, 0, 0);
            acc[rf][cf] = MFMA16(af[0][rf], bv[2], acc[rf][cf], 0, 0, 0);
            acc[rf][cf] = MFMA16(af[1][rf], bv[1], acc[rf][cf], 0, 0, 0);
            acc[rf][cf] = MFMA16(af[2][rf], bv[0], acc[rf][cf], 0, 0, 0);
          }
        }
      }
    }
    __syncthreads();
  }
  us16* o16 = (us16*)outp; float* of = (float*)outp;
#pragma unroll
  for (int rf = 0; rf < 2; ++rf)
#pragma unroll
    for (int cf = 0; cf < 4; ++cf)
#pragma unroll
      for (int i = 0; i < 4; ++i){
        int r = rb + wv * 32 + rf * 16 + kg * 4 + i;
        int c = cb + cf * 16 + r0;
        if (r >= M || c >= N) continue;
        float v = acc[rf][cf][i];
        if (mode == 0){
          of[(size_t)r * ldd + c] = fmaxf(v + aux[c], 0.f);
        } else if (mode == 1){
          v = fmaxf(v + aux[c], 0.f);
          us16 s0, s1, s2; split3(v, s0, s1, s2);
          size_t b2 = (size_t)r * ldd + c;
          o16[b2] = s0; o16[X2PL + b2] = s1; o16[2 * X2PL + b2] = s2;
        } else if (mode == 2){
          us16 hh = f2h(v); float rem = v - h2f(hh); us16 hl = f2h(rem);
          size_t b2 = (size_t)r * 1024 + c;
          o16[b2] = hh; o16[WTPL + b2] = hl;
        } else if (mode == 3){
          float w = v + (r < 1024 ? aux[(size_t)r * 4096 + c] : 0.f);
          int pc = (c & 1023) * 4 + (c >> 10);
          us16 s0, s1, s2; split3(w, s0, s1, s2);
          size_t b2 = (size_t)pc * 2048 + 512 + r;
          o16[b2] = s0; o16[WTPL + b2] = s1; o16[2 * WTPL + b2] = s2;
        } else if (mode == 4){
          o16[(size_t)r * ldd + c] = f2bf(v);
        } else if (mode == 5){
          of[((size_t)(r & 31) * 200 + (r >> 5)) * 80 + c] = v + aux[c];
        } else {
          of[(size_t)r * ldd + c] = v;
        }
      }
}

// ---------------- split arrive / wait (two-level, last-arriver-releases) ----
// arr layout (u32): group counters (set*8+g)*32, roots (48+set)*32,
// releases (56+set)*32. __syncthreads drains each wave's stores (compiler
// emits vmcnt(0) before s_barrier), so arrival implies data at MALL.
__device__ __forceinline__ void arrv(u32* arr, int set, u32 ng, u32 ep, int tid, int blk){
  __syncthreads();
  if (tid == 0){
    int g = (blk >> 5) & 7;
    u32 old = __hip_atomic_fetch_add(&arr[(set * 8 + g) * 32], 1u, __ATOMIC_RELAXED, AGT);
    if (old == 32u * ep - 1u){
      u32 r = __hip_atomic_fetch_add(&arr[(48 + set) * 32], 1u, __ATOMIC_RELAXED, AGT);
      if (r == ng * ep - 1u)
        sigflag(&arr[(56 + set) * 32], ep);
    }
  }
}
__device__ __forceinline__ void waitrel(u32* arr, int set, u32 ep, int tid){
  if (tid == 0){
    while (aload32(&arr[(56 + set) * 32]) < ep) __builtin_amdgcn_s_sleep(2);
    __builtin_amdgcn_sched_barrier(0);
  }
  __syncthreads();
}

// ---------------- persistent scan kernel ----------------
struct CoopA {
  const us16 *wta, *wqt, *x2p, *kh, *kl;
  const float *mem, *vatt, *bperm;
  us16 *hpr;
  float *ucr, *sr, *qr, *cbuf, *hf32;
  u32 *arr;
};

__global__ void __launch_bounds__(512, 1) k_coop(CoopA a){
  __shared__ us16 khi[32][1024];
  __shared__ us16 klo[32][1024];
  __shared__ float zp[8][512];
  __shared__ float esc[16];
  __shared__ float rs_lds[32];

  // one-time invalidate: kill stale lines from a previous graph replay
  __builtin_amdgcn_fence(__ATOMIC_ACQUIRE, "agent");

  const int tid = threadIdx.x, blk = blockIdx.x;
  const int wv = tid >> 6, lane = tid & 63;
  const int r0 = lane & 15, kg = lane >> 4;
  const int b16 = blk >> 4, s0c = (blk & 15) * 16;   // phase-C identity (16b x 16s)
  const int colbase = blk * 16;
  const int u0 = lane * 16;

  // WTA slice pinned in registers for all 200 steps (96 VGPRs/thread).
  bf16x8 wr[8][3];
#pragma unroll
  for (int ks = 0; ks < 8; ++ks){
    const size_t wb = (size_t)(colbase + r0) * 2048 + (size_t)wv * 256 + ks * 32 + kg * 8;
#pragma unroll
    for (int p = 0; p < 3; ++p)
      wr[ks][p] = pin_reg(*(const bf16x8*)&a.wta[(size_t)p * WTPL + wb]);
  }

  // keys: rows 0..15 = G0 slice (b16, s0c..), rows 16..31 = G1 (b16+16, s0c..)
  {
    for (int i = tid; i < 4096; i += 512){
      int r = i >> 7, c8 = (i & 127) * 8;
      int gb = (r < 16) ? b16 : (16 + b16);
      int s  = s0c + (r & 15);
      const size_t kb = ((size_t)(gb * 256 + s)) * 1024 + c8;
      *(bf16x8*)&khi[r][c8] = *(const bf16x8*)&a.kh[kb];
      *(bf16x8*)&klo[r][c8] = *(const bf16x8*)&a.kl[kb];
    }
  }
  __syncthreads();

  // ---- half-phase bodies ----
  auto phaseA = [&](int g, int t){
    if (tid < 16) rs_lds[g * 16 + tid] = 1.f / a.sr[(size_t)t * 32 + g * 16 + tid];
    __syncthreads();
    const int gr = g * 16;
    f32x4 acc = (f32x4){0.f, 0.f, 0.f, 0.f};
#pragma unroll
    for (int ks = 0; ks < 8; ++ks){
      const int kf = wv * 256 + ks * 32 + kg * 8;
      bf16x8 w0 = wr[ks][0], w1 = wr[ks][1], w2 = wr[ks][2];
      bf16x8 a0, a1, a2;
      if (wv < 2){
        const size_t xb = ((size_t)(gr + r0) * 200 + t) * 512 + kf;
        a0 = *(const bf16x8*)&a.x2p[xb];
        a1 = *(const bf16x8*)&a.x2p[X2PL + xb];
        a2 = *(const bf16x8*)&a.x2p[2 * X2PL + xb];
      } else if (wv < 6){
        const int hk = kf - 512;
        const us16* hb = a.hpr + (size_t)t * 98304 + (size_t)(gr + r0) * 1024 + hk;
        a0 = ld16(hb); a1 = ld16(hb + 32768); a2 = ld16(hb + 65536);
      } else {
        const int ek = kf - 1536;
        const float* up = a.ucr + (size_t)t * 16384 + (size_t)(gr + r0) * 512 + ek;
        f32_frag3(up, rs_lds[gr + r0], a0, a1, a2);
      }
      acc = MFMA16(a0, w0, acc, 0,0,0); acc = MFMA16(a0, w1, acc, 0,0,0);
      acc = MFMA16(a1, w0, acc, 0,0,0); acc = MFMA16(a0, w2, acc, 0,0,0);
      acc = MFMA16(a1, w1, acc, 0,0,0); acc = MFMA16(a2, w0, acc, 0,0,0);
    }
#pragma unroll
    for (int i = 0; i < 4; ++i)
      zp[wv][(kg * 4 + i) * 16 + r0] = acc[i];
    __syncthreads();
    float z = 0.f;
    if (tid < 256){
#pragma unroll
      for (int w = 0; w < 8; ++w) z += zp[w][tid];
      z += a.bperm[colbase + (tid & 15)];
    }
    __syncthreads();
    if (tid < 256) zp[0][tid] = z;
    __syncthreads();
    if (tid < 64){
      int bl = tid >> 2, ul = tid & 3, u = blk * 4 + ul;
      int b = gr + bl;
      float zi = zp[0][bl * 16 + ul * 4 + 0];
      float zf = zp[0][bl * 16 + ul * 4 + 1];
      float zg = zp[0][bl * 16 + ul * 4 + 2];
      float zo = zp[0][bl * 16 + ul * 4 + 3];
      float co = a.cbuf[b * 1024 + u];
      float cn = sigf(zf) * co + sigf(zi) * tanh_fast(zg);
      float hn = sigf(zo) * tanh_fast(cn);
      a.cbuf[b * 1024 + u] = cn;
      a.hf32[b * 1024 + u] = hn;
      us16 s0, s1, s2; split3(hn, s0, s1, s2);
      us16* hb = a.hpr + (size_t)(t + 1) * 98304 + b * 1024 + u;
      astore16(hb, s0);
      astore16(hb + 32768, s1);
      astore16(hb + 65536, s2);
    }
  };

  auto phaseB = [&](int g, int t, int colb){
    const int gr = g * 16;
    f32x4 acc = (f32x4){0.f, 0.f, 0.f, 0.f};
#pragma unroll
    for (int ks = 0; ks < 4; ++ks){
      const int kf = wv * 128 + ks * 32 + kg * 8;
      const size_t wb = (size_t)(colb + r0) * 1024 + kf;
      bf16x8 w0 = *(const bf16x8*)&a.wqt[wb];
      bf16x8 w1 = *(const bf16x8*)&a.wqt[WQPL + wb];
      bf16x8 w2 = *(const bf16x8*)&a.wqt[2 * WQPL + wb];
      const us16* hb = a.hpr + (size_t)(t + 1) * 98304 + (size_t)(gr + r0) * 1024 + kf;
      bf16x8 a0 = ld16(hb), a1 = ld16(hb + 32768), a2 = ld16(hb + 65536);
      acc = MFMA16(a0, w0, acc, 0,0,0); acc = MFMA16(a0, w1, acc, 0,0,0);
      acc = MFMA16(a1, w0, acc, 0,0,0); acc = MFMA16(a0, w2, acc, 0,0,0);
      acc = MFMA16(a1, w1, acc, 0,0,0); acc = MFMA16(a2, w0, acc, 0,0,0);
    }
#pragma unroll
    for (int i = 0; i < 4; ++i)
      zp[wv][(kg * 4 + i) * 16 + r0] = acc[i];
    __syncthreads();
    if (tid < 256){
      float q = 0.f;
#pragma unroll
      for (int w = 0; w < 8; ++w) q += zp[w][tid];
      astoref(&a.qr[(size_t)t * 32768 + (size_t)(gr + (tid >> 4)) * 1024 + colb + (tid & 15)], q);
    }
  };

  auto phaseC = [&](int g, int t){
    const int b = g * 16 + b16;
    float qv[16], vv[16];
    {
      const float* qp = a.qr + (size_t)t * 32768 + (size_t)b * 1024 + u0;
      float4 q0 = *(const float4*)qp;
      float4 q1 = *(const float4*)(qp + 4);
      float4 q2 = *(const float4*)(qp + 8);
      float4 q3 = *(const float4*)(qp + 12);
      qv[0]=q0.x; qv[1]=q0.y; qv[2]=q0.z; qv[3]=q0.w;
      qv[4]=q1.x; qv[5]=q1.y; qv[6]=q1.z; qv[7]=q1.w;
      qv[8]=q2.x; qv[9]=q2.y; qv[10]=q2.z; qv[11]=q2.w;
      qv[12]=q3.x; qv[13]=q3.y; qv[14]=q3.z; qv[15]=q3.w;
      float4 v0 = *(const float4*)(a.vatt + u0);
      float4 v1 = *(const float4*)(a.vatt + u0 + 4);
      float4 v2 = *(const float4*)(a.vatt + u0 + 8);
      float4 v3 = *(const float4*)(a.vatt + u0 + 12);
      vv[0]=v0.x; vv[1]=v0.y; vv[2]=v0.z; vv[3]=v0.w;
      vv[4]=v1.x; vv[5]=v1.y; vv[6]=v1.z; vv[7]=v1.w;
      vv[8]=v2.x; vv[9]=v2.y; vv[10]=v2.z; vv[11]=v2.w;
      vv[12]=v3.x; vv[13]=v3.y; vv[14]=v3.z; vv[15]=v3.w;
    }
#pragma unroll
    for (int m = 0; m < 2; ++m){
      const int sl = wv * 2 + m;
      const int kr = g * 16 + sl;
      bf16x8 h0 = *(const bf16x8*)&khi[kr][u0];
      bf16x8 h1 = *(const bf16x8*)&khi[kr][u0 + 8];
      bf16x8 l0 = *(const bf16x8*)&klo[kr][u0];
      bf16x8 l1 = *(const bf16x8*)&klo[kr][u0 + 8];
      float part = 0.f;
#pragma unroll
      for (int j = 0; j < 8; ++j){
        float kva = h2f((us16)h0[j]) + h2f((us16)l0[j]);
        part += vv[j] * tanh_fast(kva + qv[j]);
        float kvb = h2f((us16)h1[j]) + h2f((us16)l1[j]);
        part += vv[8 + j] * tanh_fast(kvb + qv[8 + j]);
      }
#pragma unroll
      for (int off = 32; off; off >>= 1) part += __shfl_xor(part, off);
      if (lane == 0) esc[sl] = __expf(part);    // max-free softmax
    }
    __syncthreads();
    if (tid == 0){
      float bs = 0.f;
#pragma unroll
      for (int i = 0; i < 16; ++i) bs += esc[i];
      aaddf(&a.sr[(size_t)(t + 1) * 32 + b], bs);
    }
    {
      float ac0 = 0.f, ac1 = 0.f;
      const float* mrow = a.mem + ((size_t)(b * 256 + s0c)) * 512 + tid;
#pragma unroll
      for (int j = 0; j < 16; j += 2){
        ac0 += esc[j]     * mrow[(size_t)j * 512];
        ac1 += esc[j + 1] * mrow[(size_t)(j + 1) * 512];
      }
      aaddf(&a.ucr[(size_t)(t + 1) * 16384 + b * 512 + tid], ac0 + ac1);
    }
    __syncthreads();   // esc reuse safety for next half-phase
  };

  // ---- pipelined scan ----
  for (int t = 0; t < 200; ++t){
    const u32 ep = (u32)(t + 1);
    waitrel(a.arr, SC0, (u32)t, tid);
    phaseA(0, t);
    arrv(a.arr, SA0, 8, ep, tid, blk);
    waitrel(a.arr, SC1, (u32)t, tid);
    phaseA(1, t);
    arrv(a.arr, SA1, 8, ep, tid, blk);
    if (blk < 64){
      waitrel(a.arr, SA0, ep, tid);
      phaseB(0, t, blk * 16);
      arrv(a.arr, SB0, 2, ep, tid, blk);
    } else if (blk < 128){
      waitrel(a.arr, SA1, ep, tid);
      phaseB(1, t, (blk - 64) * 16);
      arrv(a.arr, SB1, 2, ep, tid, blk);
    }
    waitrel(a.arr, SB0, ep, tid);
    phaseC(0, t);
    arrv(a.arr, SC0, 8, ep, tid, blk);
    waitrel(a.arr, SB1, ep, tid);
    phaseC(1, t);
    arrv(a.arr, SC1, 8, ep, tid, blk);
  }
}

// ---------------- hist reconstruction (post-loop, pure function of rolls) ----
__global__ void k_hist(const us16* __restrict__ hpr, const float* __restrict__ ucr,
                       const float* __restrict__ sr, us16* __restrict__ hist){
  int row = blockIdx.x;                 // 0..6431 = t*32 + b
  int t = row >> 5, b = row & 31;
  float rs = 1.f / sr[(size_t)t * 32 + b];
  for (int c = threadIdx.x; c < 1536; c += 256){
    us16 v;
    if (c < 1024) v = hpr[(size_t)t * 98304 + b * 1024 + c];       // plane0 = f2bf(h)
    else          v = f2bf(ucr[(size_t)t * 16384 + b * 512 + (c - 1024)] * rs);
    hist[(size_t)row * 1536 + c] = v;
  }
}

__global__ void k_copy_hc(const float* __restrict__ h, const float* __restrict__ c,
                          float* __restrict__ out){
  int i = blockIdx.x * 256 + threadIdx.x;
  if (i < 32768){
    out[512000 + i] = h[i];
    out[544768 + i] = c[i];
  }
}

// ---------------------------------------------------------------------------
extern "C" void kernel_launch(void* const* d_in, const int* in_sizes, int n_in,
                              void* d_out, int out_size, void* d_ws, size_t ws_size,
                              hipStream_t stream){
  const float* inputs = (const float*)d_in[0];
  const float* memory = (const float*)d_in[1];
  const float* W1     = (const float*)d_in[2];
  const float* b1     = (const float*)d_in[3];
  const float* W2     = (const float*)d_in[4];
  const float* b2     = (const float*)d_in[5];
  const float* Wx     = (const float*)d_in[6];
  const float* Wh     = (const float*)d_in[7];
  const float* b_lstm = (const float*)d_in[8];
  const float* Wm     = (const float*)d_in[9];
  const float* Wq     = (const float*)d_in[10];
  const float* v_att  = (const float*)d_in[11];
  const float* Wa     = (const float*)d_in[12];
  const float* Wp     = (const float*)d_in[13];
  const float* bp     = (const float*)d_in[14];
  float* out = (float*)d_out;
  char* ws = (char*)d_ws;
  if (ws_size < TOTAL_WS) return;

  us16* WTA    = (us16*)(ws + OFF_WTA);
  us16* WQT    = (us16*)(ws + OFF_WQT);
  us16* X2P    = (us16*)(ws + OFF_X2P);
  us16* KEYH   = (us16*)(ws + OFF_KEYH);
  float* X1    = (float*)(ws + OFF_X1);
  us16* HIST   = (us16*)(ws + OFF_HIST);
  us16* HPR    = (us16*)(ws + OFF_HPR);
  float* UCR   = (float*)(ws + OFF_UCR);
  float* SR    = (float*)(ws + OFF_SR);
  float* QR    = (float*)(ws + OFF_QR);
  float* CB    = (float*)(ws + OFF_CB);
  float* HF    = (float*)(ws + OFF_HF);
  us16* WAPN   = (us16*)(ws + OFF_WAPN);
  float* BPM   = (float*)(ws + OFF_BPERM);
  u32*  ARR    = (u32*)(ws + OFF_ARR);

  k_zero_init<<<256, 256, 0, stream>>>((u32*)HPR, UCR, SR, CB, ARR);
  k_bperm<<<16, 256, 0, stream>>>(b_lstm, BPM);
  k_transp3<<<dim3(32, 32), 256, 0, stream>>>(Wq, WQT, 1024, 1024, 1024, (long long)WQPL, 0);
  k_transp3<<<dim3(128, 16), 256, 0, stream>>>(Wx, WTA, 512, 4096, 2048, (long long)WTPL, 1);

  // fold: WTA rows 512..2047 = [Wh + WaTop@Wxb ; WaBot@Wxb], gate-permuted, triple-split
  k_gemm3<3,1,1><<<dim3(12, 64), 256, 0, stream>>>(Wa, Wx + (size_t)512 * 4096, WTA,
                                                   1536, 4096, 1024, 3, Wh, 0);
  // WapN = Wa @ Wp  [1536][80] bf16
  k_gemm3<3,1,1><<<dim3(12, 2), 256, 0, stream>>>(Wa, Wp, WAPN, 1536, 80, 1024, 4, nullptr, 80);
  // prenet 1: x1 = relu(inputs @ W1 + b1)  f32
  k_gemm3<3,1,1><<<dim3(50, 16), 256, 0, stream>>>(inputs, W1, X1, 6400, 1024, 80, 0, b1, 1024);
  // prenet 2: x2 = relu(x1 @ W2 + b2) -> triple planes
  k_gemm3<3,1,1><<<dim3(50, 8), 256, 0, stream>>>(X1, W2, X2P, 6400, 512, 1024, 1, b2, 512);
  // keys = memory @ Wm -> fp16 pair (overwrites X1 alias region; X1 dead now)
  k_gemm3<3,1,1><<<dim3(64, 16), 256, 0, stream>>>(memory, Wm, KEYH, 8192, 1024, 512, 2, nullptr, 1024);

  CoopA ca;
  ca.wta = WTA; ca.wqt = WQT; ca.x2p = X2P; ca.kh = KEYH; ca.kl = KEYH + WTPL;
  ca.mem = memory; ca.vatt = v_att; ca.bperm = BPM;
  ca.hpr = HPR; ca.ucr = UCR; ca.sr = SR;
  ca.qr = QR; ca.cbuf = CB; ca.hf32 = HF; ca.arr = ARR;
  void* args[] = {(void*)&ca};
  hipLaunchCooperativeKernel((const void*)k_coop, dim3(256), dim3(512), args, 0, stream);

  // rebuild hist from rolling buffers
  k_hist<<<6432, 256, 0, stream>>>(HPR, UCR, SR, HIST);
  // mel = hist[1..200] @ WapN + bp
  k_gemm3<1,0,0><<<dim3(50, 2), 256, 0, stream>>>(HIST + (size_t)32 * 1536, WAPN, out,
                                                  6400, 80, 1536, 5, bp, 0);
  // attn = hist[200] @ Wa
  k_gemm3<1,0,1><<<dim3(1, 16), 256, 0, stream>>>(HIST + (size_t)200 * 32 * 1536, Wa,
                                                  out + 577536, 32, 1024, 1536, 6, nullptr, 1024);
  k_copy_hc<<<128, 256, 0, stream>>>(HF, CB, out);
}